// Round 3
// baseline (1845.066 us; speedup 1.0000x reference)
//
#include <hip/hip_runtime.h>
#include <hip/hip_bf16.h>
#include <cstdint>
#include <cstddef>

#define A_REAL 50000
#define A_PAD  50048      // 391 * 128
#define MTILES 391
#define NBOND  6
#define HD     512
#define FATOM  133
#define FBOND  14
#define KWI    160        // 133 padded to mult of 32
#define KWH    544        // 512+14 padded
#define KWO    672        // 512+133 padded
#define NMOL   2000
#define MOLPAD 2048
#define APM    25
#define NHID   256

typedef __bf16 bf16x8 __attribute__((ext_vector_type(8)));
typedef float  f32x4  __attribute__((ext_vector_type(4)));
typedef short  short8 __attribute__((ext_vector_type(8)));
typedef short  short4v __attribute__((ext_vector_type(4)));

__device__ __forceinline__ float b2f(unsigned short u) {
  return __uint_as_float(((unsigned int)u) << 16);
}
__device__ __forceinline__ unsigned short f2b(float f) {
  unsigned int x = __float_as_uint(f);
  unsigned int r = (x + 0x7fffu + ((x >> 16) & 1u)) >> 16;
  return (unsigned short)r;
}

// ---------------- zero the pad regions (every call, deterministic) -----------
__global__ void zero_pads(unsigned short* __restrict__ wNei,
                          unsigned short* __restrict__ wWoIn,
                          unsigned short* __restrict__ wEnc)
{
  const int t = blockIdx.x * 256 + threadIdx.x;
  if (t < 48 * KWH)  wNei [(size_t)A_REAL * KWH  + t] = 0;
  if (t < 48 * KWO)  wWoIn[(size_t)A_REAL * KWO  + t] = 0;
  if (t < 48 * 1024) wEnc [(size_t)NMOL  * 1024  + t] = 0;
}

// ---------------- f32 weights -> padded bf16 ---------------------------------
// mode 0: plain pad.  mode 1: Wo reorder (src [512][645] = [f_atoms|a_msg] ->
// dst cols 0..511 = a_msg part, 512..644 = f_atoms part, rest 0)
__global__ void convw(unsigned short* __restrict__ dst, const float* __restrict__ src,
                      int Ksrc, int ldd, int rows, int mode)
{
  const int idx = blockIdx.x * 256 + threadIdx.x;
  if (idx >= rows * ldd) return;
  const int n = idx / ldd, k = idx % ldd;
  float v = 0.f;
  if (mode == 0) {
    if (k < Ksrc) v = src[(size_t)n * Ksrc + k];
  } else {
    if (k < 512)      v = src[(size_t)n * 645 + 133 + k];
    else if (k < 645) v = src[(size_t)n * 645 + (k - 512)];
  }
  dst[(size_t)n * ldd + k] = f2b(v);
}

// ---------------- f_atoms -> wWoIn cols 512..671 (bf16, padded) --------------
__global__ void atoms_prep(unsigned short* __restrict__ wWoIn, const float* __restrict__ f_atoms)
{
  const int idx = blockIdx.x * 256 + threadIdx.x;
  if (idx >= A_PAD * KWI) return;
  const int r = idx / KWI, c = idx % KWI;
  float v = 0.f;
  if (r < A_REAL && c < FATOM) v = f_atoms[(size_t)r * FATOM + c];
  wWoIn[(size_t)r * KWO + 512 + c] = f2b(v);
}

// ---------------- bond gather-sum -> wNei cols 512..543 (once per side) ------
__global__ void bond_gather(unsigned short* __restrict__ wNei, const float* __restrict__ f_bonds,
                            const int* __restrict__ a2b)
{
  const int a = blockIdx.x * 256 + threadIdx.x;
  if (a >= A_REAL) return;
  float acc[FBOND];
  #pragma unroll
  for (int c = 0; c < FBOND; ++c) acc[c] = 0.f;
  #pragma unroll
  for (int j = 0; j < NBOND; ++j) {
    const int b = a2b[a * NBOND + j];
    const float* row = f_bonds + (size_t)b * FBOND;
    #pragma unroll
    for (int c = 0; c < FBOND; ++c) acc[c] += row[c];
  }
  unsigned short* d = wNei + (size_t)a * KWH + 512;
  #pragma unroll
  for (int c = 0; c < FBOND; ++c) d[c] = f2b(acc[c]);
  #pragma unroll
  for (int c = FBOND; c < 32; ++c) d[c] = 0;   // zero pad cols 526..543
}

// ---------------- 6-neighbor gather-sum of msg -> dst cols 0..511 ------------
__launch_bounds__(256)
__global__ void gather6(unsigned short* __restrict__ dst, int dstLd,
                        const unsigned short* __restrict__ msg,
                        const int* __restrict__ a2a)
{
  const int a    = blockIdx.x * 4 + (threadIdx.x >> 6);
  const int lane = threadIdx.x & 63;
  const int* idx = a2a + a * NBOND;
  float acc[8] = {0.f,0.f,0.f,0.f,0.f,0.f,0.f,0.f};
  #pragma unroll
  for (int j = 0; j < NBOND; ++j) {
    const int r = idx[j];
    short8 v = *reinterpret_cast<const short8*>(msg + (size_t)r * HD + lane * 8);
    #pragma unroll
    for (int e = 0; e < 8; ++e) acc[e] += b2f((unsigned short)v[e]);
  }
  short8 o;
  #pragma unroll
  for (int e = 0; e < 8; ++e) o[e] = (short)f2b(acc[e]);
  *reinterpret_cast<short8*>(dst + (size_t)a * dstLd + lane * 8) = o;
}

// ---------------- bf16 MFMA GEMM, m97 structure ------------------------------
// C[M x N] = A[M x K] * W[N x K]^T  (bf16 in, fp32 accum)
// 128x128 tile, BK=32, 256 thr / 4 waves, global_load_lds width-16 staging.
// 1D grid + bijective chunked XCD swizzle (FETCH 141->38 MB measured r2).
// Epilogue: C restaged through LDS in f32 with 16B-slot XOR swizzle
//   (row,col) -> slot (col>>2)^(row&7): writes 2-way (free), reads are
//   consecutive-16B-per-lane f32x4 (conflict-free), stores 8B coalesced.
//   (r2's unswizzled version cost 65M conflict cycles = +100us/dispatch.)
// MODE 0 (Wi): outA=x (bias only), outB=msg=relu(x)
// MODE 1 (Wh): outB=x (read),      outA=msg=relu(acc + bias + x)
// MODE 2 (Wo/FFN1): outA = relu(acc + bias)
union GemmShared {
  struct { unsigned short a[128 * 32]; unsigned short b[128 * 32]; } st;
  float c[64 * 128];
};

template<int MODE, int NTN>
__launch_bounds__(256)
__global__ void gemm_bf16(const unsigned short* __restrict__ A, int lda,
                          const unsigned short* __restrict__ W, int ldb,
                          const float* __restrict__ bias, int K,
                          unsigned short* __restrict__ outA,
                          unsigned short* __restrict__ outB,
                          int outLd)
{
  __shared__ GemmShared sh;
  const int tid  = threadIdx.x;
  const int wav  = tid >> 6;
  const int lane = tid & 63;
  const int wm = wav >> 1, wn = wav & 1;

  // bijective chunked XCD swizzle (m204)
  const int nwg = gridDim.x;
  const int id  = blockIdx.x;
  const int q = nwg >> 3, r = nwg & 7;
  const int xcd = id & 7, jj = id >> 3;
  const int gid = (xcd < r ? xcd * (q + 1) : r * (q + 1) + (xcd - r) * q) + jj;
  const int bxt = gid / NTN;
  const int byt = gid - bxt * NTN;
  const size_t tileM = (size_t)bxt * 128;
  const int n0 = byt * 128;

  const int srow = lane >> 2;          // staging: row within 16-row chunk
  const int scol = (lane & 3) * 8;     // staging: col (bf16) within 32
  const int fr = lane & 15;            // fragment row/col
  const int fk = (lane >> 4) * 8;      // fragment k base

  f32x4 acc[4][4];
  #pragma unroll
  for (int m = 0; m < 4; ++m)
    #pragma unroll
    for (int n = 0; n < 4; ++n)
      acc[m][n] = (f32x4){0.f, 0.f, 0.f, 0.f};

  const unsigned short* Abase = A + tileM * (size_t)lda;
  const unsigned short* Wbase = W + (size_t)n0 * (size_t)ldb;

  for (int k0 = 0; k0 < K; k0 += 32) {
    #pragma unroll
    for (int i = 0; i < 2; ++i) {
      const int c = i * 4 + wav;            // chunk 0..7, 1024B each
      const int rr = c * 16 + srow;         // tile row 0..127
      const unsigned short* ga = Abase + (size_t)rr * lda + (k0 + scol);
      const unsigned short* gb = Wbase + (size_t)rr * ldb + (k0 + scol);
      __builtin_amdgcn_global_load_lds(
          (const __attribute__((address_space(1))) unsigned int*)ga,
          (__attribute__((address_space(3))) unsigned int*)&sh.st.a[c * 512], 16, 0, 0);
      __builtin_amdgcn_global_load_lds(
          (const __attribute__((address_space(1))) unsigned int*)gb,
          (__attribute__((address_space(3))) unsigned int*)&sh.st.b[c * 512], 16, 0, 0);
    }
    __syncthreads();
    bf16x8 af[4], bfm[4];
    #pragma unroll
    for (int m = 0; m < 4; ++m)
      af[m] = *reinterpret_cast<const bf16x8*>(&sh.st.a[(wm * 64 + m * 16 + fr) * 32 + fk]);
    #pragma unroll
    for (int n = 0; n < 4; ++n)
      bfm[n] = *reinterpret_cast<const bf16x8*>(&sh.st.b[(wn * 64 + n * 16 + fr) * 32 + fk]);
    #pragma unroll
    for (int m = 0; m < 4; ++m)
      #pragma unroll
      for (int n = 0; n < 4; ++n)
        acc[m][n] = __builtin_amdgcn_mfma_f32_16x16x32_bf16(af[m], bfm[n], acc[m][n], 0, 0, 0);
    __syncthreads();
  }

  // bias into registers (f32, no extra rounding)
  const int rb = (lane >> 4) * 4;
  const int cI = lane & 15;
  #pragma unroll
  for (int n = 0; n < 4; ++n) {
    const float bv = bias[n0 + wn * 64 + n * 16 + cI];
    #pragma unroll
    for (int m = 0; m < 4; ++m)
      #pragma unroll
      for (int i = 0; i < 4; ++i)
        acc[m][n][i] += bv;
  }

  // two 64-row passes: swizzled f32 LDS restage -> coalesced 16B reads/8B stores
  #pragma unroll
  for (int p2 = 0; p2 < 2; ++p2) {
    __syncthreads();
    if (wm == p2) {
      #pragma unroll
      for (int m = 0; m < 4; ++m)
        #pragma unroll
        for (int n = 0; n < 4; ++n) {
          const int col = wn * 64 + n * 16 + cI;
          #pragma unroll
          for (int i = 0; i < 4; ++i) {
            const int row = m * 16 + rb + i;
            const int slot = (col >> 2) ^ (row & 7);
            sh.c[row * 128 + slot * 4 + (col & 3)] = acc[m][n][i];
          }
        }
    }
    __syncthreads();
    #pragma unroll
    for (int u = 0; u < 8; ++u) {
      const int fidx = u * 1024 + tid * 4;     // flat f32 index in 64x128 pass
      const int row  = fidx >> 7;              // 0..63
      const int slot = (fidx & 127) >> 2;
      const f32x4 v = *reinterpret_cast<const f32x4*>(
          &sh.c[row * 128 + ((slot ^ (row & 7)) << 2)]);
      const size_t rowg = tileM + p2 * 64 + row;
      const size_t off = rowg * (size_t)outLd + (size_t)(n0 + (fidx & 127));
      if (MODE == 0) {
        short4v o0, o1;
        #pragma unroll
        for (int e = 0; e < 4; ++e) {
          o0[e] = (short)f2b(v[e]);
          o1[e] = (short)f2b(fmaxf(v[e], 0.f));
        }
        *reinterpret_cast<short4v*>(&outA[off]) = o0;
        *reinterpret_cast<short4v*>(&outB[off]) = o1;
      } else if (MODE == 1) {
        const short4v xv = *reinterpret_cast<const short4v*>(&outB[off]);
        short4v o;
        #pragma unroll
        for (int e = 0; e < 4; ++e) {
          const float t = v[e] + b2f((unsigned short)xv[e]);
          o[e] = (short)f2b(fmaxf(t, 0.f));
        }
        *reinterpret_cast<short4v*>(&outA[off]) = o;
      } else {
        short4v o;
        #pragma unroll
        for (int e = 0; e < 4; ++e) o[e] = (short)f2b(fmaxf(v[e], 0.f));
        *reinterpret_cast<short4v*>(&outA[off]) = o;
      }
    }
  }
}

// ---------------- per-molecule mean over 25 atoms -> enc (bf16) --------------
__launch_bounds__(256)
__global__ void readout(const unsigned short* __restrict__ h, unsigned short* __restrict__ enc)
{
  const int mol = blockIdx.x;
  const int t = threadIdx.x;               // cols 2t, 2t+1
  const unsigned short* base = h + (size_t)mol * APM * HD + t * 2;
  float s0 = 0.f, s1 = 0.f;
  #pragma unroll
  for (int r = 0; r < APM; ++r) {
    unsigned int v = *reinterpret_cast<const unsigned int*>(base + (size_t)r * HD);
    s0 += b2f((unsigned short)(v & 0xffffu));
    s1 += b2f((unsigned short)(v >> 16));
  }
  s0 *= (1.f / 25.f);
  s1 *= (1.f / 25.f);
  unsigned int o = (unsigned int)f2b(s0) | ((unsigned int)f2b(s1) << 16);
  *reinterpret_cast<unsigned int*>(enc + (size_t)mol * 1024 + t * 2) = o;
}

// ---------------- final dot with ffn2 ----------------------------------------
__launch_bounds__(256)
__global__ void ffn2_red(const unsigned short* __restrict__ ff1, const float* __restrict__ w2,
                         const float* __restrict__ b2, float* __restrict__ out)
{
  __shared__ float red[256];
  const int mol = blockIdx.x, t = threadIdx.x;
  red[t] = b2f(ff1[(size_t)mol * NHID + t]) * w2[t];
  __syncthreads();
  #pragma unroll
  for (int s = 128; s > 0; s >>= 1) {
    if (t < s) red[t] += red[t + s];
    __syncthreads();
  }
  if (t == 0) out[mol] = red[0] + b2[0];
}

// -----------------------------------------------------------------------------
extern "C" void kernel_launch(void* const* d_in, const int* in_sizes, int n_in,
                              void* d_out, int out_size, void* d_ws, size_t ws_size,
                              hipStream_t stream)
{
  (void)in_sizes; (void)n_in; (void)out_size; (void)ws_size;
  unsigned char* p = (unsigned char*)d_ws;
  auto take = [&](size_t bytes) -> unsigned short* {
    unsigned short* r = (unsigned short*)p;
    p += (bytes + 1023) & ~(size_t)1023;
    return r;
  };
  unsigned short* wX    = take((size_t)A_PAD * HD  * 2);   // x  (bf16)
  unsigned short* wMsg  = take((size_t)A_PAD * HD  * 2);   // msg (bf16)
  unsigned short* wNei  = take((size_t)A_PAD * KWH * 2);   // nei / (alias) h
  unsigned short* wH    = wNei;
  unsigned short* wWoIn = take((size_t)A_PAD * KWO * 2);   // [a_msg | f_atoms | pad]
  unsigned short* wEnc  = take((size_t)MOLPAD * 1024 * 2); // bf16 [2048][1024]
  unsigned short* wFF1  = take((size_t)MOLPAD * NHID * 2);
  unsigned short* wWiB  = take((size_t)512 * KWI * 2);
  unsigned short* wWhB  = take((size_t)512 * KWH * 2);
  unsigned short* wWoB  = take((size_t)512 * KWO * 2);
  unsigned short* wF1B  = take((size_t)NHID * 1024 * 2);

  zero_pads<<<192, 256, 0, stream>>>(wNei, wWoIn, wEnc);

  for (int side = 0; side < 2; ++side) {
    const float* f_atoms = (const float*)d_in[side * 10 + 0];
    const float* f_bonds = (const float*)d_in[side * 10 + 1];
    const int*   a2a     = (const int*)  d_in[side * 10 + 2];
    const int*   a2b     = (const int*)  d_in[side * 10 + 3];
    const float* Wi_w    = (const float*)d_in[side * 10 + 4];
    const float* Wi_b    = (const float*)d_in[side * 10 + 5];
    const float* Wh_w    = (const float*)d_in[side * 10 + 6];
    const float* Wh_b    = (const float*)d_in[side * 10 + 7];
    const float* Wo_w    = (const float*)d_in[side * 10 + 8];
    const float* Wo_b    = (const float*)d_in[side * 10 + 9];

    convw<<<(512 * KWI) / 256, 256, 0, stream>>>(wWiB, Wi_w, FATOM, KWI, 512, 0);
    convw<<<(512 * KWH) / 256, 256, 0, stream>>>(wWhB, Wh_w, 526, KWH, 512, 0);
    convw<<<(512 * KWO) / 256, 256, 0, stream>>>(wWoB, Wo_w, 645, KWO, 512, 1);
    atoms_prep<<<(A_PAD * KWI) / 256, 256, 0, stream>>>(wWoIn, f_atoms);
    bond_gather<<<(A_REAL + 255) / 256, 256, 0, stream>>>(wNei, f_bonds, a2b);

    // x = f_atoms @ Wi^T + b ; msg = relu(x)   (A read from wWoIn cols 512..671)
    gemm_bf16<0, 4><<<MTILES * 4, 256, 0, stream>>>(wWoIn + 512, KWO, wWiB, KWI,
                                                    Wi_b, KWI, wX, wMsg, HD);
    for (int it = 0; it < 3; ++it) {
      gather6<<<A_REAL / 4, 256, 0, stream>>>(wNei, KWH, wMsg, a2a);
      gemm_bf16<1, 4><<<MTILES * 4, 256, 0, stream>>>(wNei, KWH, wWhB, KWH,
                                                      Wh_b, KWH, wMsg, wX, HD);
    }
    gather6<<<A_REAL / 4, 256, 0, stream>>>(wWoIn, KWO, wMsg, a2a);
    gemm_bf16<2, 4><<<MTILES * 4, 256, 0, stream>>>(wWoIn, KWO, wWoB, KWO,
                                                    Wo_b, KWO, wH, nullptr, HD);
    readout<<<NMOL, 256, 0, stream>>>(wH, wEnc + side * HD);
  }

  const float* ffn1_w = (const float*)d_in[20];
  const float* ffn1_b = (const float*)d_in[21];
  const float* ffn2_w = (const float*)d_in[22];
  const float* ffn2_b = (const float*)d_in[23];

  convw<<<(NHID * 1024) / 256, 256, 0, stream>>>(wF1B, ffn1_w, 1024, 1024, NHID, 0);
  gemm_bf16<2, 2><<<32, 256, 0, stream>>>(wEnc, 1024, wF1B, 1024,
                                          ffn1_b, 1024, wFF1, nullptr, NHID);
  ffn2_red<<<NMOL, 256, 0, stream>>>(wFF1, ffn2_w, ffn2_b, (float*)d_out);
}

// Round 4
// 1253.570 us; speedup vs baseline: 1.4718x; 1.4718x over previous
//
#include <hip/hip_runtime.h>
#include <hip/hip_bf16.h>
#include <cstdint>
#include <cstddef>

#define A_REAL 50000
#define A_PAD  50048      // 391 * 128
#define MTILES 391
#define NBOND  6
#define HD     512
#define FATOM  133
#define FBOND  14
#define KWI    160        // 133 padded to mult of 32
#define KWH    544        // 512+14 padded
#define KWO    672        // 512+133 padded
#define NMOL   2000
#define MOLPAD 2048
#define APM    25
#define NHID   256

typedef __bf16 bf16x8 __attribute__((ext_vector_type(8)));
typedef float  f32x4  __attribute__((ext_vector_type(4)));
typedef short  short8 __attribute__((ext_vector_type(8)));
typedef short  short4v __attribute__((ext_vector_type(4)));

__device__ __forceinline__ float b2f(unsigned short u) {
  return __uint_as_float(((unsigned int)u) << 16);
}
__device__ __forceinline__ unsigned short f2b(float f) {
  unsigned int x = __float_as_uint(f);
  unsigned int r = (x + 0x7fffu + ((x >> 16) & 1u)) >> 16;
  return (unsigned short)r;
}

// ---------------- zero the pad regions (every call, deterministic) -----------
__global__ void zero_pads(unsigned short* __restrict__ wNei,
                          unsigned short* __restrict__ wWoIn,
                          unsigned short* __restrict__ wEnc)
{
  const int t = blockIdx.x * 256 + threadIdx.x;
  if (t < 48 * KWH)  wNei [(size_t)A_REAL * KWH  + t] = 0;
  if (t < 48 * KWO)  wWoIn[(size_t)A_REAL * KWO  + t] = 0;
  if (t < 48 * 1024) wEnc [(size_t)NMOL  * 1024  + t] = 0;
}

// ---------------- f32 weights -> padded bf16 ---------------------------------
// mode 0: plain pad.  mode 1: Wo reorder (src [512][645] = [f_atoms|a_msg] ->
// dst cols 0..511 = a_msg part, 512..644 = f_atoms part, rest 0)
__global__ void convw(unsigned short* __restrict__ dst, const float* __restrict__ src,
                      int Ksrc, int ldd, int rows, int mode)
{
  const int idx = blockIdx.x * 256 + threadIdx.x;
  if (idx >= rows * ldd) return;
  const int n = idx / ldd, k = idx % ldd;
  float v = 0.f;
  if (mode == 0) {
    if (k < Ksrc) v = src[(size_t)n * Ksrc + k];
  } else {
    if (k < 512)      v = src[(size_t)n * 645 + 133 + k];
    else if (k < 645) v = src[(size_t)n * 645 + (k - 512)];
  }
  dst[(size_t)n * ldd + k] = f2b(v);
}

// ---------------- f_atoms -> wWoIn cols 512..671 (bf16, padded) --------------
__global__ void atoms_prep(unsigned short* __restrict__ wWoIn, const float* __restrict__ f_atoms)
{
  const int idx = blockIdx.x * 256 + threadIdx.x;
  if (idx >= A_PAD * KWI) return;
  const int r = idx / KWI, c = idx % KWI;
  float v = 0.f;
  if (r < A_REAL && c < FATOM) v = f_atoms[(size_t)r * FATOM + c];
  wWoIn[(size_t)r * KWO + 512 + c] = f2b(v);
}

// ---------------- bond gather-sum -> wNei cols 512..543 (once per side) ------
__global__ void bond_gather(unsigned short* __restrict__ wNei, const float* __restrict__ f_bonds,
                            const int* __restrict__ a2b)
{
  const int a = blockIdx.x * 256 + threadIdx.x;
  if (a >= A_REAL) return;
  float acc[FBOND];
  #pragma unroll
  for (int c = 0; c < FBOND; ++c) acc[c] = 0.f;
  #pragma unroll
  for (int j = 0; j < NBOND; ++j) {
    const int b = a2b[a * NBOND + j];
    const float* row = f_bonds + (size_t)b * FBOND;
    #pragma unroll
    for (int c = 0; c < FBOND; ++c) acc[c] += row[c];
  }
  unsigned short* d = wNei + (size_t)a * KWH + 512;
  #pragma unroll
  for (int c = 0; c < FBOND; ++c) d[c] = f2b(acc[c]);
  #pragma unroll
  for (int c = FBOND; c < 32; ++c) d[c] = 0;   // zero pad cols 526..543
}

// ------- 6-neighbor gather-sum of relu(state) -> dst cols 0..511 -------------
// relu applied here (relu(bf16(s)) == bf16(relu(s))) so GEMMs can store
// pre-activation state and we skip the separate msg tensor entirely.
__launch_bounds__(256)
__global__ void gather6(unsigned short* __restrict__ dst, int dstLd,
                        const unsigned short* __restrict__ state,
                        const int* __restrict__ a2a)
{
  const int a    = blockIdx.x * 4 + (threadIdx.x >> 6);
  const int lane = threadIdx.x & 63;
  const int* idx = a2a + a * NBOND;
  float acc[8] = {0.f,0.f,0.f,0.f,0.f,0.f,0.f,0.f};
  #pragma unroll
  for (int j = 0; j < NBOND; ++j) {
    const int r = idx[j];
    short8 v = *reinterpret_cast<const short8*>(state + (size_t)r * HD + lane * 8);
    #pragma unroll
    for (int e = 0; e < 8; ++e) acc[e] += fmaxf(b2f((unsigned short)v[e]), 0.f);
  }
  short8 o;
  #pragma unroll
  for (int e = 0; e < 8; ++e) o[e] = (short)f2b(acc[e]);
  *reinterpret_cast<short8*>(dst + (size_t)a * dstLd + lane * 8) = o;
}

// ---------------- bf16 MFMA GEMM, m97 structure ------------------------------
// C[M x N] = A[M x K] * W[N x K]^T  (bf16 in, fp32 accum)
// 128x128 tile, BK=32, 256 thr / 4 waves, global_load_lds width-16 staging.
// 1D grid + bijective chunked XCD swizzle (FETCH 141->38 MB, measured r2).
// OPERAND-SWAPPED MFMA: mfma(W_frag, A_frag) yields C^T's fragment, i.e.
// lane = M-row, the 4 acc regs = 4 consecutive N cols -> each lane packs
// 4 bf16 into one 8B store (32 VMEM ops/thread vs r1's 128 scalar 2B ops).
// No LDS restage (r2/r3's restage cost ~60M conflict cycles = +90us).
// MODE 0 (Wi): outA = acc + bias              (x, pre-relu state)
// MODE 1 (Wh): outA = acc + bias + outB(=x)   (pre-relu state; relu in gather)
// MODE 2 (Wo/FFN1): outA = relu(acc + bias)
struct GemmShared { unsigned short a[128 * 32]; unsigned short b[128 * 32]; };

template<int MODE, int NTN>
__launch_bounds__(256)
__global__ void gemm_bf16(const unsigned short* __restrict__ A, int lda,
                          const unsigned short* __restrict__ W, int ldb,
                          const float* __restrict__ bias, int K,
                          unsigned short* __restrict__ outA,
                          const unsigned short* __restrict__ outB,
                          int outLd)
{
  __shared__ GemmShared sh;
  const int tid  = threadIdx.x;
  const int wav  = tid >> 6;
  const int lane = tid & 63;
  const int wm = wav >> 1, wn = wav & 1;

  // bijective chunked XCD swizzle (m204)
  const int nwg = gridDim.x;
  const int id  = blockIdx.x;
  const int q = nwg >> 3, r = nwg & 7;
  const int xcd = id & 7, jj = id >> 3;
  const int gid = (xcd < r ? xcd * (q + 1) : r * (q + 1) + (xcd - r) * q) + jj;
  const int bxt = gid / NTN;
  const int byt = gid - bxt * NTN;
  const size_t tileM = (size_t)bxt * 128;
  const int n0 = byt * 128;

  const int srow = lane >> 2;          // staging: row within 16-row chunk
  const int scol = (lane & 3) * 8;     // staging: col (bf16) within 32
  const int fr = lane & 15;            // fragment row/col
  const int fk = (lane >> 4) * 8;      // fragment k base

  f32x4 acc[4][4];
  #pragma unroll
  for (int m = 0; m < 4; ++m)
    #pragma unroll
    for (int n = 0; n < 4; ++n)
      acc[m][n] = (f32x4){0.f, 0.f, 0.f, 0.f};

  const unsigned short* Abase = A + tileM * (size_t)lda;
  const unsigned short* Wbase = W + (size_t)n0 * (size_t)ldb;

  for (int k0 = 0; k0 < K; k0 += 32) {
    #pragma unroll
    for (int i = 0; i < 2; ++i) {
      const int c = i * 4 + wav;            // chunk 0..7, 1024B each
      const int rr = c * 16 + srow;         // tile row 0..127
      const unsigned short* ga = Abase + (size_t)rr * lda + (k0 + scol);
      const unsigned short* gb = Wbase + (size_t)rr * ldb + (k0 + scol);
      __builtin_amdgcn_global_load_lds(
          (const __attribute__((address_space(1))) unsigned int*)ga,
          (__attribute__((address_space(3))) unsigned int*)&sh.a[c * 512], 16, 0, 0);
      __builtin_amdgcn_global_load_lds(
          (const __attribute__((address_space(1))) unsigned int*)gb,
          (__attribute__((address_space(3))) unsigned int*)&sh.b[c * 512], 16, 0, 0);
    }
    __syncthreads();
    bf16x8 af[4], bfm[4];
    #pragma unroll
    for (int m = 0; m < 4; ++m)
      af[m] = *reinterpret_cast<const bf16x8*>(&sh.a[(wm * 64 + m * 16 + fr) * 32 + fk]);
    #pragma unroll
    for (int n = 0; n < 4; ++n)
      bfm[n] = *reinterpret_cast<const bf16x8*>(&sh.b[(wn * 64 + n * 16 + fr) * 32 + fk]);
    // operand-swapped: acc[m][n] reg i, lane l =
    //   C[tileM + wm*64 + m*16 + (l&15)][n0 + wn*64 + n*16 + (l>>4)*4 + i]
    #pragma unroll
    for (int m = 0; m < 4; ++m)
      #pragma unroll
      for (int n = 0; n < 4; ++n)
        acc[m][n] = __builtin_amdgcn_mfma_f32_16x16x32_bf16(bfm[n], af[m], acc[m][n], 0, 0, 0);
    __syncthreads();
  }

  const int erow = lane & 15;
  const int ecol = (lane >> 4) * 4;
  #pragma unroll
  for (int m = 0; m < 4; ++m) {
    const size_t rowg = tileM + wm * 64 + m * 16 + erow;
    #pragma unroll
    for (int n = 0; n < 4; ++n) {
      const int colg = n0 + wn * 64 + n * 16 + ecol;
      const f32x4 bv = *reinterpret_cast<const f32x4*>(&bias[colg]);
      const size_t off = rowg * (size_t)outLd + colg;
      float v[4];
      #pragma unroll
      for (int e = 0; e < 4; ++e) v[e] = acc[m][n][e] + bv[e];
      short4v o;
      if (MODE == 0) {
        #pragma unroll
        for (int e = 0; e < 4; ++e) o[e] = (short)f2b(v[e]);
      } else if (MODE == 1) {
        const short4v xv = *reinterpret_cast<const short4v*>(&outB[off]);
        #pragma unroll
        for (int e = 0; e < 4; ++e) o[e] = (short)f2b(v[e] + b2f((unsigned short)xv[e]));
      } else {
        #pragma unroll
        for (int e = 0; e < 4; ++e) o[e] = (short)f2b(fmaxf(v[e], 0.f));
      }
      *reinterpret_cast<short4v*>(&outA[off]) = o;
    }
  }
}

// ---------------- per-molecule mean over 25 atoms -> enc (bf16) --------------
__launch_bounds__(256)
__global__ void readout(const unsigned short* __restrict__ h, unsigned short* __restrict__ enc)
{
  const int mol = blockIdx.x;
  const int t = threadIdx.x;               // cols 2t, 2t+1
  const unsigned short* base = h + (size_t)mol * APM * HD + t * 2;
  float s0 = 0.f, s1 = 0.f;
  #pragma unroll
  for (int r = 0; r < APM; ++r) {
    unsigned int v = *reinterpret_cast<const unsigned int*>(base + (size_t)r * HD);
    s0 += b2f((unsigned short)(v & 0xffffu));
    s1 += b2f((unsigned short)(v >> 16));
  }
  s0 *= (1.f / 25.f);
  s1 *= (1.f / 25.f);
  unsigned int o = (unsigned int)f2b(s0) | ((unsigned int)f2b(s1) << 16);
  *reinterpret_cast<unsigned int*>(enc + (size_t)mol * 1024 + t * 2) = o;
}

// ---------------- final dot with ffn2 ----------------------------------------
__launch_bounds__(256)
__global__ void ffn2_red(const unsigned short* __restrict__ ff1, const float* __restrict__ w2,
                         const float* __restrict__ b2, float* __restrict__ out)
{
  __shared__ float red[256];
  const int mol = blockIdx.x, t = threadIdx.x;
  red[t] = b2f(ff1[(size_t)mol * NHID + t]) * w2[t];
  __syncthreads();
  #pragma unroll
  for (int s = 128; s > 0; s >>= 1) {
    if (t < s) red[t] += red[t + s];
    __syncthreads();
  }
  if (t == 0) out[mol] = red[0] + b2[0];
}

// -----------------------------------------------------------------------------
extern "C" void kernel_launch(void* const* d_in, const int* in_sizes, int n_in,
                              void* d_out, int out_size, void* d_ws, size_t ws_size,
                              hipStream_t stream)
{
  (void)in_sizes; (void)n_in; (void)out_size; (void)ws_size;
  unsigned char* p = (unsigned char*)d_ws;
  auto take = [&](size_t bytes) -> unsigned short* {
    unsigned short* r = (unsigned short*)p;
    p += (bytes + 1023) & ~(size_t)1023;
    return r;
  };
  unsigned short* wX    = take((size_t)A_PAD * HD  * 2);   // x = Wi out (pre-relu)
  unsigned short* wS    = take((size_t)A_PAD * HD  * 2);   // s_t (pre-relu state)
  unsigned short* wNei  = take((size_t)A_PAD * KWH * 2);   // nei / (alias) h
  unsigned short* wH    = wNei;
  unsigned short* wWoIn = take((size_t)A_PAD * KWO * 2);   // [a_msg | f_atoms | pad]
  unsigned short* wEnc  = take((size_t)MOLPAD * 1024 * 2); // bf16 [2048][1024]
  unsigned short* wFF1  = take((size_t)MOLPAD * NHID * 2);
  unsigned short* wWiB  = take((size_t)512 * KWI * 2);
  unsigned short* wWhB  = take((size_t)512 * KWH * 2);
  unsigned short* wWoB  = take((size_t)512 * KWO * 2);
  unsigned short* wF1B  = take((size_t)NHID * 1024 * 2);

  zero_pads<<<192, 256, 0, stream>>>(wNei, wWoIn, wEnc);

  for (int side = 0; side < 2; ++side) {
    const float* f_atoms = (const float*)d_in[side * 10 + 0];
    const float* f_bonds = (const float*)d_in[side * 10 + 1];
    const int*   a2a     = (const int*)  d_in[side * 10 + 2];
    const int*   a2b     = (const int*)  d_in[side * 10 + 3];
    const float* Wi_w    = (const float*)d_in[side * 10 + 4];
    const float* Wi_b    = (const float*)d_in[side * 10 + 5];
    const float* Wh_w    = (const float*)d_in[side * 10 + 6];
    const float* Wh_b    = (const float*)d_in[side * 10 + 7];
    const float* Wo_w    = (const float*)d_in[side * 10 + 8];
    const float* Wo_b    = (const float*)d_in[side * 10 + 9];

    convw<<<(512 * KWI) / 256, 256, 0, stream>>>(wWiB, Wi_w, FATOM, KWI, 512, 0);
    convw<<<(512 * KWH) / 256, 256, 0, stream>>>(wWhB, Wh_w, 526, KWH, 512, 0);
    convw<<<(512 * KWO) / 256, 256, 0, stream>>>(wWoB, Wo_w, 645, KWO, 512, 1);
    atoms_prep<<<(A_PAD * KWI) / 256, 256, 0, stream>>>(wWoIn, f_atoms);
    bond_gather<<<(A_REAL + 255) / 256, 256, 0, stream>>>(wNei, f_bonds, a2b);

    // x = f_atoms @ Wi^T + b  (pre-relu; A read from wWoIn cols 512..671)
    gemm_bf16<0, 4><<<MTILES * 4, 256, 0, stream>>>(wWoIn + 512, KWO, wWiB, KWI,
                                                    Wi_b, KWI, wX, nullptr, HD);
    for (int it = 0; it < 3; ++it) {
      gather6<<<A_REAL / 4, 256, 0, stream>>>(wNei, KWH, it == 0 ? wX : wS, a2a);
      gemm_bf16<1, 4><<<MTILES * 4, 256, 0, stream>>>(wNei, KWH, wWhB, KWH,
                                                      Wh_b, KWH, wS, wX, HD);
    }
    gather6<<<A_REAL / 4, 256, 0, stream>>>(wWoIn, KWO, wS, a2a);
    gemm_bf16<2, 4><<<MTILES * 4, 256, 0, stream>>>(wWoIn, KWO, wWoB, KWO,
                                                    Wo_b, KWO, wH, nullptr, HD);
    readout<<<NMOL, 256, 0, stream>>>(wH, wEnc + side * HD);
  }

  const float* ffn1_w = (const float*)d_in[20];
  const float* ffn1_b = (const float*)d_in[21];
  const float* ffn2_w = (const float*)d_in[22];
  const float* ffn2_b = (const float*)d_in[23];

  convw<<<(NHID * 1024) / 256, 256, 0, stream>>>(wF1B, ffn1_w, 1024, 1024, NHID, 0);
  gemm_bf16<2, 2><<<32, 256, 0, stream>>>(wEnc, 1024, wF1B, 1024,
                                          ffn1_b, 1024, wFF1, nullptr, NHID);
  ffn2_red<<<NMOL, 256, 0, stream>>>(wFF1, ffn2_w, ffn2_b, (float*)d_out);
}

// Round 5
// 1095.095 us; speedup vs baseline: 1.6848x; 1.1447x over previous
//
#include <hip/hip_runtime.h>
#include <hip/hip_bf16.h>
#include <cstdint>
#include <cstddef>

#define A_REAL 50000
#define A_PAD  50048      // 391 * 128
#define MTILES 391
#define NBOND  6
#define HD     512
#define FATOM  133
#define FBOND  14
#define KWI    160        // 133 padded to mult of 32
#define KWH    544        // 512+14 padded
#define KWO    672        // 512+133 padded
#define NMOL   2000
#define MOLPAD 2048
#define APM    25
#define NHID   256

typedef __bf16 bf16x8 __attribute__((ext_vector_type(8)));
typedef float  f32x4  __attribute__((ext_vector_type(4)));
typedef short  short8 __attribute__((ext_vector_type(8)));
typedef short  short4v __attribute__((ext_vector_type(4)));

__device__ __forceinline__ float b2f(unsigned short u) {
  return __uint_as_float(((unsigned int)u) << 16);
}
__device__ __forceinline__ unsigned short f2b(float f) {
  unsigned int x = __float_as_uint(f);
  unsigned int r = (x + 0x7fffu + ((x >> 16) & 1u)) >> 16;
  return (unsigned short)r;
}

// ---------------- zero the pad regions (every call, deterministic) -----------
__global__ void zero_pads(unsigned short* __restrict__ wNei,
                          unsigned short* __restrict__ wWoIn,
                          unsigned short* __restrict__ wEnc)
{
  const int t = blockIdx.x * 256 + threadIdx.x;
  if (t < 48 * KWH)  wNei [(size_t)A_REAL * KWH  + t] = 0;
  if (t < 48 * KWO)  wWoIn[(size_t)A_REAL * KWO  + t] = 0;
  if (t < 48 * 1024) wEnc [(size_t)NMOL  * 1024  + t] = 0;
}

// ---------------- f32 weights -> padded bf16 ---------------------------------
// mode 0: plain pad.  mode 1: Wo reorder (src [512][645] = [f_atoms|a_msg] ->
// dst cols 0..511 = a_msg part, 512..644 = f_atoms part, rest 0)
__global__ void convw(unsigned short* __restrict__ dst, const float* __restrict__ src,
                      int Ksrc, int ldd, int rows, int mode)
{
  const int idx = blockIdx.x * 256 + threadIdx.x;
  if (idx >= rows * ldd) return;
  const int n = idx / ldd, k = idx % ldd;
  float v = 0.f;
  if (mode == 0) {
    if (k < Ksrc) v = src[(size_t)n * Ksrc + k];
  } else {
    if (k < 512)      v = src[(size_t)n * 645 + 133 + k];
    else if (k < 645) v = src[(size_t)n * 645 + (k - 512)];
  }
  dst[(size_t)n * ldd + k] = f2b(v);
}

// ---------------- f_atoms -> wWoIn cols 512..671 (bf16, padded) --------------
__global__ void atoms_prep(unsigned short* __restrict__ wWoIn, const float* __restrict__ f_atoms)
{
  const int idx = blockIdx.x * 256 + threadIdx.x;
  if (idx >= A_PAD * KWI) return;
  const int r = idx / KWI, c = idx % KWI;
  float v = 0.f;
  if (r < A_REAL && c < FATOM) v = f_atoms[(size_t)r * FATOM + c];
  wWoIn[(size_t)r * KWO + 512 + c] = f2b(v);
}

// ---------------- bond gather-sum -> wNei cols 512..543 (once per side) ------
__global__ void bond_gather(unsigned short* __restrict__ wNei, const float* __restrict__ f_bonds,
                            const int* __restrict__ a2b)
{
  const int a = blockIdx.x * 256 + threadIdx.x;
  if (a >= A_REAL) return;
  float acc[FBOND];
  #pragma unroll
  for (int c = 0; c < FBOND; ++c) acc[c] = 0.f;
  #pragma unroll
  for (int j = 0; j < NBOND; ++j) {
    const int b = a2b[a * NBOND + j];
    const float* row = f_bonds + (size_t)b * FBOND;
    #pragma unroll
    for (int c = 0; c < FBOND; ++c) acc[c] += row[c];
  }
  unsigned short* d = wNei + (size_t)a * KWH + 512;
  #pragma unroll
  for (int c = 0; c < FBOND; ++c) d[c] = f2b(acc[c]);
  #pragma unroll
  for (int c = FBOND; c < 32; ++c) d[c] = 0;   // zero pad cols 526..543
}

// ------- 6-neighbor gather-sum of relu(state) -> dst cols 0..511 -------------
// relu applied here (relu(bf16(s)) == bf16(relu(s))) so GEMMs can store
// pre-activation state and we skip the separate msg tensor entirely.
__launch_bounds__(256)
__global__ void gather6(unsigned short* __restrict__ dst, int dstLd,
                        const unsigned short* __restrict__ state,
                        const int* __restrict__ a2a)
{
  const int a    = blockIdx.x * 4 + (threadIdx.x >> 6);
  const int lane = threadIdx.x & 63;
  const int* idx = a2a + a * NBOND;
  float acc[8] = {0.f,0.f,0.f,0.f,0.f,0.f,0.f,0.f};
  #pragma unroll
  for (int j = 0; j < NBOND; ++j) {
    const int r = idx[j];
    short8 v = *reinterpret_cast<const short8*>(state + (size_t)r * HD + lane * 8);
    #pragma unroll
    for (int e = 0; e < 8; ++e) acc[e] += fmaxf(b2f((unsigned short)v[e]), 0.f);
  }
  short8 o;
  #pragma unroll
  for (int e = 0; e < 8; ++e) o[e] = (short)f2b(acc[e]);
  *reinterpret_cast<short8*>(dst + (size_t)a * dstLd + lane * 8) = o;
}

// ---------------- bf16 MFMA GEMM, depth-2 prefetch pipeline ------------------
// C[M x N] = A[M x K] * W[N x K]^T  (bf16 in, fp32 accum)
// 128x128 tile, BK=32, 256 thr / 4 waves.
// r4 post-mortem: the 2-barrier m97 loop was LATENCY-bound (93us vs 15us HBM
// floor, MfmaUtil 14%): vmcnt(0) drained before any compute each K-step.
// Now: 3-deep LDS ring, stage(t+2) issued post-barrier, counted vmcnt(4)
// (T3+T4): next tile's loads stay in flight across the barrier, giving each
// load ~2 compute phases to land. Raw s_barrier + asm "memory" fences.
// Hazard audit: stage(t+2) overwrites iter-(t-1)'s buffer -- safe, all waves'
// ds_reads of t-1 completed (lgkm dep) before they reached the iter-t barrier.
// Per-wave vmcnt(4) BEFORE barrier => everyone's stage(t) visible after it.
// OPERAND-SWAPPED MFMA: lane = M-row, 4 acc regs = 4 consecutive N cols ->
// 8B coalesced epilogue stores, no LDS restage.
// MODE 0 (Wi): outA = acc + bias              (x, pre-relu state)
// MODE 1 (Wh): outA = acc + bias + outB(=x)   (pre-relu state; relu in gather)
// MODE 2 (Wo/FFN1): outA = relu(acc + bias)
template<int MODE, int NTN>
__launch_bounds__(256)
__global__ void gemm_bf16(const unsigned short* __restrict__ A, int lda,
                          const unsigned short* __restrict__ W, int ldb,
                          const float* __restrict__ bias, int K,
                          unsigned short* __restrict__ outA,
                          const unsigned short* __restrict__ outB,
                          int outLd)
{
  __shared__ alignas(16) unsigned short lA[3][128 * 32];
  __shared__ alignas(16) unsigned short lB[3][128 * 32];
  const int tid  = threadIdx.x;
  const int wav  = tid >> 6;
  const int lane = tid & 63;
  const int wm = wav >> 1, wn = wav & 1;

  // bijective chunked XCD swizzle (m204)
  const int nwg = gridDim.x;
  const int id  = blockIdx.x;
  const int q = nwg >> 3, r = nwg & 7;
  const int xcd = id & 7, jj = id >> 3;
  const int gid = (xcd < r ? xcd * (q + 1) : r * (q + 1) + (xcd - r) * q) + jj;
  const int bxt = gid / NTN;
  const int byt = gid - bxt * NTN;
  const size_t tileM = (size_t)bxt * 128;
  const int n0 = byt * 128;

  const int srow = lane >> 2;          // staging: row within 16-row chunk
  const int scol = (lane & 3) * 8;     // staging: col (bf16) within 32
  const int fr = lane & 15;            // fragment row/col
  const int fk = (lane >> 4) * 8;      // fragment k base

  f32x4 acc[4][4];
  #pragma unroll
  for (int m = 0; m < 4; ++m)
    #pragma unroll
    for (int n = 0; n < 4; ++n)
      acc[m][n] = (f32x4){0.f, 0.f, 0.f, 0.f};

  const unsigned short* Abase = A + tileM * (size_t)lda;
  const unsigned short* Wbase = W + (size_t)n0 * (size_t)ldb;
  const int nt = K >> 5;

  // 4 global_load_lds per thread per stage (A,B interleaved x2)
  auto stage = [&](int t, int buf) {
    const int k0 = t * 32;
    #pragma unroll
    for (int i = 0; i < 2; ++i) {
      const int c = i * 4 + wav;            // chunk 0..7, 1024B each
      const int rr = c * 16 + srow;         // tile row 0..127
      const unsigned short* ga = Abase + (size_t)rr * lda + (k0 + scol);
      const unsigned short* gb = Wbase + (size_t)rr * ldb + (k0 + scol);
      __builtin_amdgcn_global_load_lds(
          (const __attribute__((address_space(1))) unsigned int*)ga,
          (__attribute__((address_space(3))) unsigned int*)&lA[buf][c * 512], 16, 0, 0);
      __builtin_amdgcn_global_load_lds(
          (const __attribute__((address_space(1))) unsigned int*)gb,
          (__attribute__((address_space(3))) unsigned int*)&lB[buf][c * 512], 16, 0, 0);
    }
  };

  stage(0, 0);
  if (nt > 1) stage(1, 1);

  int buf = 0;
  for (int t = 0; t < nt; ++t) {
    // wait for stage(t) only; stage(t+1)'s 4 ops may remain in flight
    if (t + 1 < nt) asm volatile("s_waitcnt vmcnt(4)" ::: "memory");
    else            asm volatile("s_waitcnt vmcnt(0)" ::: "memory");
    __builtin_amdgcn_s_barrier();
    asm volatile("" ::: "memory");

    bf16x8 af[4], bfm[4];
    #pragma unroll
    for (int m = 0; m < 4; ++m)
      af[m] = *reinterpret_cast<const bf16x8*>(&lA[buf][(wm * 64 + m * 16 + fr) * 32 + fk]);
    #pragma unroll
    for (int n = 0; n < 4; ++n)
      bfm[n] = *reinterpret_cast<const bf16x8*>(&lB[buf][(wn * 64 + n * 16 + fr) * 32 + fk]);

    if (t + 2 < nt) {
      int b2v = buf + 2; if (b2v >= 3) b2v -= 3;
      stage(t + 2, b2v);
    }

    // operand-swapped: acc[m][n] reg i, lane l =
    //   C[tileM + wm*64 + m*16 + (l&15)][n0 + wn*64 + n*16 + (l>>4)*4 + i]
    #pragma unroll
    for (int m = 0; m < 4; ++m)
      #pragma unroll
      for (int n = 0; n < 4; ++n)
        acc[m][n] = __builtin_amdgcn_mfma_f32_16x16x32_bf16(bfm[n], af[m], acc[m][n], 0, 0, 0);

    buf = (buf == 2) ? 0 : buf + 1;
  }

  const int erow = lane & 15;
  const int ecol = (lane >> 4) * 4;
  #pragma unroll
  for (int m = 0; m < 4; ++m) {
    const size_t rowg = tileM + wm * 64 + m * 16 + erow;
    #pragma unroll
    for (int n = 0; n < 4; ++n) {
      const int colg = n0 + wn * 64 + n * 16 + ecol;
      const f32x4 bv = *reinterpret_cast<const f32x4*>(&bias[colg]);
      const size_t off = rowg * (size_t)outLd + colg;
      float v[4];
      #pragma unroll
      for (int e = 0; e < 4; ++e) v[e] = acc[m][n][e] + bv[e];
      short4v o;
      if (MODE == 0) {
        #pragma unroll
        for (int e = 0; e < 4; ++e) o[e] = (short)f2b(v[e]);
      } else if (MODE == 1) {
        const short4v xv = *reinterpret_cast<const short4v*>(&outB[off]);
        #pragma unroll
        for (int e = 0; e < 4; ++e) o[e] = (short)f2b(v[e] + b2f((unsigned short)xv[e]));
      } else {
        #pragma unroll
        for (int e = 0; e < 4; ++e) o[e] = (short)f2b(fmaxf(v[e], 0.f));
      }
      *reinterpret_cast<short4v*>(&outA[off]) = o;
    }
  }
}

// ---------------- per-molecule mean over 25 atoms -> enc (bf16) --------------
__launch_bounds__(256)
__global__ void readout(const unsigned short* __restrict__ h, unsigned short* __restrict__ enc)
{
  const int mol = blockIdx.x;
  const int t = threadIdx.x;               // cols 2t, 2t+1
  const unsigned short* base = h + (size_t)mol * APM * HD + t * 2;
  float s0 = 0.f, s1 = 0.f;
  #pragma unroll
  for (int r = 0; r < APM; ++r) {
    unsigned int v = *reinterpret_cast<const unsigned int*>(base + (size_t)r * HD);
    s0 += b2f((unsigned short)(v & 0xffffu));
    s1 += b2f((unsigned short)(v >> 16));
  }
  s0 *= (1.f / 25.f);
  s1 *= (1.f / 25.f);
  unsigned int o = (unsigned int)f2b(s0) | ((unsigned int)f2b(s1) << 16);
  *reinterpret_cast<unsigned int*>(enc + (size_t)mol * 1024 + t * 2) = o;
}

// ---------------- final dot with ffn2 ----------------------------------------
__launch_bounds__(256)
__global__ void ffn2_red(const unsigned short* __restrict__ ff1, const float* __restrict__ w2,
                         const float* __restrict__ b2, float* __restrict__ out)
{
  __shared__ float red[256];
  const int mol = blockIdx.x, t = threadIdx.x;
  red[t] = b2f(ff1[(size_t)mol * NHID + t]) * w2[t];
  __syncthreads();
  #pragma unroll
  for (int s = 128; s > 0; s >>= 1) {
    if (t < s) red[t] += red[t + s];
    __syncthreads();
  }
  if (t == 0) out[mol] = red[0] + b2[0];
}

// -----------------------------------------------------------------------------
extern "C" void kernel_launch(void* const* d_in, const int* in_sizes, int n_in,
                              void* d_out, int out_size, void* d_ws, size_t ws_size,
                              hipStream_t stream)
{
  (void)in_sizes; (void)n_in; (void)out_size; (void)ws_size;
  unsigned char* p = (unsigned char*)d_ws;
  auto take = [&](size_t bytes) -> unsigned short* {
    unsigned short* r = (unsigned short*)p;
    p += (bytes + 1023) & ~(size_t)1023;
    return r;
  };
  unsigned short* wX    = take((size_t)A_PAD * HD  * 2);   // x = Wi out (pre-relu)
  unsigned short* wS    = take((size_t)A_PAD * HD  * 2);   // s_t (pre-relu state)
  unsigned short* wNei  = take((size_t)A_PAD * KWH * 2);   // nei / (alias) h
  unsigned short* wH    = wNei;
  unsigned short* wWoIn = take((size_t)A_PAD * KWO * 2);   // [a_msg | f_atoms | pad]
  unsigned short* wEnc  = take((size_t)MOLPAD * 1024 * 2); // bf16 [2048][1024]
  unsigned short* wFF1  = take((size_t)MOLPAD * NHID * 2);
  unsigned short* wWiB  = take((size_t)512 * KWI * 2);
  unsigned short* wWhB  = take((size_t)512 * KWH * 2);
  unsigned short* wWoB  = take((size_t)512 * KWO * 2);
  unsigned short* wF1B  = take((size_t)NHID * 1024 * 2);

  zero_pads<<<192, 256, 0, stream>>>(wNei, wWoIn, wEnc);

  for (int side = 0; side < 2; ++side) {
    const float* f_atoms = (const float*)d_in[side * 10 + 0];
    const float* f_bonds = (const float*)d_in[side * 10 + 1];
    const int*   a2a     = (const int*)  d_in[side * 10 + 2];
    const int*   a2b     = (const int*)  d_in[side * 10 + 3];
    const float* Wi_w    = (const float*)d_in[side * 10 + 4];
    const float* Wi_b    = (const float*)d_in[side * 10 + 5];
    const float* Wh_w    = (const float*)d_in[side * 10 + 6];
    const float* Wh_b    = (const float*)d_in[side * 10 + 7];
    const float* Wo_w    = (const float*)d_in[side * 10 + 8];
    const float* Wo_b    = (const float*)d_in[side * 10 + 9];

    convw<<<(512 * KWI) / 256, 256, 0, stream>>>(wWiB, Wi_w, FATOM, KWI, 512, 0);
    convw<<<(512 * KWH) / 256, 256, 0, stream>>>(wWhB, Wh_w, 526, KWH, 512, 0);
    convw<<<(512 * KWO) / 256, 256, 0, stream>>>(wWoB, Wo_w, 645, KWO, 512, 1);
    atoms_prep<<<(A_PAD * KWI) / 256, 256, 0, stream>>>(wWoIn, f_atoms);
    bond_gather<<<(A_REAL + 255) / 256, 256, 0, stream>>>(wNei, f_bonds, a2b);

    // x = f_atoms @ Wi^T + b  (pre-relu; A read from wWoIn cols 512..671)
    gemm_bf16<0, 4><<<MTILES * 4, 256, 0, stream>>>(wWoIn + 512, KWO, wWiB, KWI,
                                                    Wi_b, KWI, wX, nullptr, HD);
    for (int it = 0; it < 3; ++it) {
      gather6<<<A_REAL / 4, 256, 0, stream>>>(wNei, KWH, it == 0 ? wX : wS, a2a);
      gemm_bf16<1, 4><<<MTILES * 4, 256, 0, stream>>>(wNei, KWH, wWhB, KWH,
                                                      Wh_b, KWH, wS, wX, HD);
    }
    gather6<<<A_REAL / 4, 256, 0, stream>>>(wWoIn, KWO, wS, a2a);
    gemm_bf16<2, 4><<<MTILES * 4, 256, 0, stream>>>(wWoIn, KWO, wWoB, KWO,
                                                    Wo_b, KWO, wH, nullptr, HD);
    readout<<<NMOL, 256, 0, stream>>>(wH, wEnc + side * HD);
  }

  const float* ffn1_w = (const float*)d_in[20];
  const float* ffn1_b = (const float*)d_in[21];
  const float* ffn2_w = (const float*)d_in[22];
  const float* ffn2_b = (const float*)d_in[23];

  convw<<<(NHID * 1024) / 256, 256, 0, stream>>>(wF1B, ffn1_w, 1024, 1024, NHID, 0);
  gemm_bf16<2, 2><<<32, 256, 0, stream>>>(wEnc, 1024, wF1B, 1024,
                                          ffn1_b, 1024, wFF1, nullptr, NHID);
  ffn2_red<<<NMOL, 256, 0, stream>>>(wFF1, ffn2_w, ffn2_b, (float*)d_out);
}

// Round 6
// 1058.962 us; speedup vs baseline: 1.7423x; 1.0341x over previous
//
#include <hip/hip_runtime.h>
#include <hip/hip_bf16.h>
#include <cstdint>
#include <cstddef>

#define A_REAL 50000
#define A_PAD  50176      // 196 * 256
#define MT256  196
#define PADROWS 176
#define NBOND  6
#define HD     512
#define FATOM  133
#define FBOND  14
#define KWI    160        // 133 padded to mult of 32
#define KWH    544        // 512+14 padded
#define KWO    672        // 512+133 padded
#define NMOL   2000
#define MOLPAD 2048
#define APM    25
#define NHID   256

typedef __bf16 bf16x8 __attribute__((ext_vector_type(8)));
typedef float  f32x4  __attribute__((ext_vector_type(4)));
typedef short  short8 __attribute__((ext_vector_type(8)));
typedef short  short4v __attribute__((ext_vector_type(4)));

__device__ __forceinline__ float b2f(unsigned short u) {
  return __uint_as_float(((unsigned int)u) << 16);
}
__device__ __forceinline__ unsigned short f2b(float f) {
  unsigned int x = __float_as_uint(f);
  unsigned int r = (x + 0x7fffu + ((x >> 16) & 1u)) >> 16;
  return (unsigned short)r;
}

// ---------------- zero the pad regions (every call, deterministic) -----------
__global__ void zero_pads(unsigned short* __restrict__ wNei,
                          unsigned short* __restrict__ wWoIn,
                          unsigned short* __restrict__ wEnc)
{
  const int t = blockIdx.x * 256 + threadIdx.x;
  if (t < PADROWS * KWH)  wNei [(size_t)A_REAL * KWH  + t] = 0;
  if (t < PADROWS * KWO)  wWoIn[(size_t)A_REAL * KWO  + t] = 0;
  if (t < 48 * 1024)      wEnc [(size_t)NMOL  * 1024  + t] = 0;
}

// ---------------- f32 weights -> padded bf16 ---------------------------------
// mode 0: plain pad.  mode 1: Wo reorder (src [512][645] = [f_atoms|a_msg] ->
// dst cols 0..511 = a_msg part, 512..644 = f_atoms part, rest 0)
__global__ void convw(unsigned short* __restrict__ dst, const float* __restrict__ src,
                      int Ksrc, int ldd, int rows, int mode)
{
  const int idx = blockIdx.x * 256 + threadIdx.x;
  if (idx >= rows * ldd) return;
  const int n = idx / ldd, k = idx % ldd;
  float v = 0.f;
  if (mode == 0) {
    if (k < Ksrc) v = src[(size_t)n * Ksrc + k];
  } else {
    if (k < 512)      v = src[(size_t)n * 645 + 133 + k];
    else if (k < 645) v = src[(size_t)n * 645 + (k - 512)];
  }
  dst[(size_t)n * ldd + k] = f2b(v);
}

// ---------------- f_atoms -> wWoIn cols 512..671 (bf16, padded) --------------
__global__ void atoms_prep(unsigned short* __restrict__ wWoIn, const float* __restrict__ f_atoms)
{
  const int idx = blockIdx.x * 256 + threadIdx.x;
  if (idx >= A_PAD * KWI) return;
  const int r = idx / KWI, c = idx % KWI;
  float v = 0.f;
  if (r < A_REAL && c < FATOM) v = f_atoms[(size_t)r * FATOM + c];
  wWoIn[(size_t)r * KWO + 512 + c] = f2b(v);
}

// ---------------- bond gather-sum -> wNei cols 512..543 (once per side) ------
__global__ void bond_gather(unsigned short* __restrict__ wNei, const float* __restrict__ f_bonds,
                            const int* __restrict__ a2b)
{
  const int a = blockIdx.x * 256 + threadIdx.x;
  if (a >= A_REAL) return;
  float acc[FBOND];
  #pragma unroll
  for (int c = 0; c < FBOND; ++c) acc[c] = 0.f;
  #pragma unroll
  for (int j = 0; j < NBOND; ++j) {
    const int b = a2b[a * NBOND + j];
    const float* row = f_bonds + (size_t)b * FBOND;
    #pragma unroll
    for (int c = 0; c < FBOND; ++c) acc[c] += row[c];
  }
  unsigned short* d = wNei + (size_t)a * KWH + 512;
  #pragma unroll
  for (int c = 0; c < FBOND; ++c) d[c] = f2b(acc[c]);
  #pragma unroll
  for (int c = FBOND; c < 32; ++c) d[c] = 0;   // zero pad cols 526..543
}

// ------- 6-neighbor gather-sum of relu(state) -> dst cols 0..511 -------------
// relu applied here (relu(bf16(s)) == bf16(relu(s))) so GEMMs can store
// pre-activation state and we skip the separate msg tensor entirely.
__launch_bounds__(256)
__global__ void gather6(unsigned short* __restrict__ dst, int dstLd,
                        const unsigned short* __restrict__ state,
                        const int* __restrict__ a2a)
{
  const int a    = blockIdx.x * 4 + (threadIdx.x >> 6);
  const int lane = threadIdx.x & 63;
  const int* idx = a2a + a * NBOND;
  float acc[8] = {0.f,0.f,0.f,0.f,0.f,0.f,0.f,0.f};
  #pragma unroll
  for (int j = 0; j < NBOND; ++j) {
    const int r = idx[j];
    short8 v = *reinterpret_cast<const short8*>(state + (size_t)r * HD + lane * 8);
    #pragma unroll
    for (int e = 0; e < 8; ++e) acc[e] += fmaxf(b2f((unsigned short)v[e]), 0.f);
  }
  short8 o;
  #pragma unroll
  for (int e = 0; e < 8; ++e) o[e] = (short)f2b(acc[e]);
  *reinterpret_cast<short8*>(dst + (size_t)a * dstLd + lane * 8) = o;
}

// ---------------- bf16 MFMA GEMM, 256x128 tile, depth-2 prefetch -------------
// C[M x N] = A[M x K] * W[N x K]^T  (bf16 in, fp32 accum)
// r5 post-mortem: 128x128/4-wave ring was still latency-bound at Occ 16%
// (5 waves/CU). Now BM=256, 8 waves/512thr: LDS ring 3x24KB = 72KB ->
// 2 blocks/CU = 16 waves/CU, ~3x the latency-hiding wave pool; W refetch
// and barrier count per FLOP halve. Counted vmcnt(3): 3 loads/thread/stage
// (2xA + 1xB), stage(t+2) issued mid-compute, wait only for stage(t).
// OPERAND-SWAPPED MFMA: lane = M-row, 4 acc regs = 4 consecutive N cols ->
// 8B coalesced epilogue stores, no LDS restage.
// MODE 0 (Wi): outA = acc + bias              (x, pre-relu state)
// MODE 1 (Wh): outA = acc + bias + outB(=x)   (pre-relu state; relu in gather)
// MODE 2 (Wo/FFN1): outA = relu(acc + bias)
template<int MODE, int NTN>
__launch_bounds__(512, 4)
__global__ void gemm_bf16(const unsigned short* __restrict__ A, int lda,
                          const unsigned short* __restrict__ W, int ldb,
                          const float* __restrict__ bias, int K,
                          unsigned short* __restrict__ outA,
                          const unsigned short* __restrict__ outB,
                          int outLd)
{
  __shared__ alignas(16) unsigned short lA[3][256 * 32];
  __shared__ alignas(16) unsigned short lB[3][128 * 32];
  const int tid  = threadIdx.x;
  const int wav  = tid >> 6;
  const int lane = tid & 63;
  const int wm = wav >> 1, wn = wav & 1;      // wm 0..3, wn 0..1

  // bijective chunked XCD swizzle (m204); NTN consecutive gids share an M-tile
  const int nwg = gridDim.x;
  const int id  = blockIdx.x;
  const int q = nwg >> 3, r = nwg & 7;
  const int xcd = id & 7, jj = id >> 3;
  const int gid = (xcd < r ? xcd * (q + 1) : r * (q + 1) + (xcd - r) * q) + jj;
  const int bxt = gid / NTN;
  const int byt = gid - bxt * NTN;
  const size_t tileM = (size_t)bxt * 256;
  const int n0 = byt * 128;

  const int srow = tid >> 2;           // staging: row (0..127) within a pass
  const int scol = (tid & 3) * 8;      // staging: col (bf16) within 32
  const int fr = lane & 15;            // fragment row
  const int fk = (lane >> 4) * 8;      // fragment k base

  f32x4 acc[4][4];
  #pragma unroll
  for (int m = 0; m < 4; ++m)
    #pragma unroll
    for (int n = 0; n < 4; ++n)
      acc[m][n] = (f32x4){0.f, 0.f, 0.f, 0.f};

  const unsigned short* Abase = A + tileM * (size_t)lda;
  const unsigned short* Wbase = W + (size_t)n0 * (size_t)ldb;
  const int nt = K >> 5;

  // 3 global_load_lds per thread per stage: A rows 0..127, A rows 128..255, B
  auto stage = [&](int t, int buf) {
    const int k0 = t * 32;
    #pragma unroll
    for (int i = 0; i < 2; ++i) {
      const int rr = i * 128 + srow;
      const unsigned short* ga = Abase + (size_t)rr * lda + (k0 + scol);
      __builtin_amdgcn_global_load_lds(
          (const __attribute__((address_space(1))) unsigned int*)ga,
          (__attribute__((address_space(3))) unsigned int*)&lA[buf][rr * 32 + scol], 16, 0, 0);
    }
    const unsigned short* gb = Wbase + (size_t)srow * ldb + (k0 + scol);
    __builtin_amdgcn_global_load_lds(
        (const __attribute__((address_space(1))) unsigned int*)gb,
        (__attribute__((address_space(3))) unsigned int*)&lB[buf][srow * 32 + scol], 16, 0, 0);
  };

  stage(0, 0);
  if (nt > 1) stage(1, 1);

  int buf = 0;
  for (int t = 0; t < nt; ++t) {
    // wait for stage(t) only; stage(t+1)'s 3 ops may remain in flight
    if (t + 1 < nt) asm volatile("s_waitcnt vmcnt(3)" ::: "memory");
    else            asm volatile("s_waitcnt vmcnt(0)" ::: "memory");
    __builtin_amdgcn_s_barrier();
    asm volatile("" ::: "memory");

    bf16x8 af[4], bfm[4];
    #pragma unroll
    for (int m = 0; m < 4; ++m)
      af[m] = *reinterpret_cast<const bf16x8*>(&lA[buf][(wm * 64 + m * 16 + fr) * 32 + fk]);
    #pragma unroll
    for (int n = 0; n < 4; ++n)
      bfm[n] = *reinterpret_cast<const bf16x8*>(&lB[buf][(wn * 64 + n * 16 + fr) * 32 + fk]);

    if (t + 2 < nt) {
      int b2v = buf + 2; if (b2v >= 3) b2v -= 3;
      stage(t + 2, b2v);
    }

    // operand-swapped: acc[m][n] reg i, lane l =
    //   C[tileM + wm*64 + m*16 + (l&15)][n0 + wn*64 + n*16 + (l>>4)*4 + i]
    #pragma unroll
    for (int m = 0; m < 4; ++m)
      #pragma unroll
      for (int n = 0; n < 4; ++n)
        acc[m][n] = __builtin_amdgcn_mfma_f32_16x16x32_bf16(bfm[n], af[m], acc[m][n], 0, 0, 0);

    buf = (buf == 2) ? 0 : buf + 1;
  }

  const int erow = lane & 15;
  const int ecol = (lane >> 4) * 4;
  #pragma unroll
  for (int m = 0; m < 4; ++m) {
    const size_t rowg = tileM + wm * 64 + m * 16 + erow;
    #pragma unroll
    for (int n = 0; n < 4; ++n) {
      const int colg = n0 + wn * 64 + n * 16 + ecol;
      const f32x4 bv = *reinterpret_cast<const f32x4*>(&bias[colg]);
      const size_t off = rowg * (size_t)outLd + colg;
      float v[4];
      #pragma unroll
      for (int e = 0; e < 4; ++e) v[e] = acc[m][n][e] + bv[e];
      short4v o;
      if (MODE == 0) {
        #pragma unroll
        for (int e = 0; e < 4; ++e) o[e] = (short)f2b(v[e]);
      } else if (MODE == 1) {
        const short4v xv = *reinterpret_cast<const short4v*>(&outB[off]);
        #pragma unroll
        for (int e = 0; e < 4; ++e) o[e] = (short)f2b(v[e] + b2f((unsigned short)xv[e]));
      } else {
        #pragma unroll
        for (int e = 0; e < 4; ++e) o[e] = (short)f2b(fmaxf(v[e], 0.f));
      }
      *reinterpret_cast<short4v*>(&outA[off]) = o;
    }
  }
}

// ---------------- per-molecule mean over 25 atoms -> enc (bf16) --------------
__launch_bounds__(256)
__global__ void readout(const unsigned short* __restrict__ h, unsigned short* __restrict__ enc)
{
  const int mol = blockIdx.x;
  const int t = threadIdx.x;               // cols 2t, 2t+1
  const unsigned short* base = h + (size_t)mol * APM * HD + t * 2;
  float s0 = 0.f, s1 = 0.f;
  #pragma unroll
  for (int r = 0; r < APM; ++r) {
    unsigned int v = *reinterpret_cast<const unsigned int*>(base + (size_t)r * HD);
    s0 += b2f((unsigned short)(v & 0xffffu));
    s1 += b2f((unsigned short)(v >> 16));
  }
  s0 *= (1.f / 25.f);
  s1 *= (1.f / 25.f);
  unsigned int o = (unsigned int)f2b(s0) | ((unsigned int)f2b(s1) << 16);
  *reinterpret_cast<unsigned int*>(enc + (size_t)mol * 1024 + t * 2) = o;
}

// ---------------- final dot with ffn2 ----------------------------------------
__launch_bounds__(256)
__global__ void ffn2_red(const unsigned short* __restrict__ ff1, const float* __restrict__ w2,
                         const float* __restrict__ b2, float* __restrict__ out)
{
  __shared__ float red[256];
  const int mol = blockIdx.x, t = threadIdx.x;
  red[t] = b2f(ff1[(size_t)mol * NHID + t]) * w2[t];
  __syncthreads();
  #pragma unroll
  for (int s = 128; s > 0; s >>= 1) {
    if (t < s) red[t] += red[t + s];
    __syncthreads();
  }
  if (t == 0) out[mol] = red[0] + b2[0];
}

// -----------------------------------------------------------------------------
extern "C" void kernel_launch(void* const* d_in, const int* in_sizes, int n_in,
                              void* d_out, int out_size, void* d_ws, size_t ws_size,
                              hipStream_t stream)
{
  (void)in_sizes; (void)n_in; (void)out_size; (void)ws_size;
  unsigned char* p = (unsigned char*)d_ws;
  auto take = [&](size_t bytes) -> unsigned short* {
    unsigned short* r = (unsigned short*)p;
    p += (bytes + 1023) & ~(size_t)1023;
    return r;
  };
  unsigned short* wX    = take((size_t)A_PAD * HD  * 2);   // x = Wi out (pre-relu)
  unsigned short* wS    = take((size_t)A_PAD * HD  * 2);   // s_t (pre-relu state)
  unsigned short* wNei  = take((size_t)A_PAD * KWH * 2);   // nei / (alias) h
  unsigned short* wH    = wNei;
  unsigned short* wWoIn = take((size_t)A_PAD * KWO * 2);   // [a_msg | f_atoms | pad]
  unsigned short* wEnc  = take((size_t)MOLPAD * 1024 * 2); // bf16 [2048][1024]
  unsigned short* wFF1  = take((size_t)MOLPAD * NHID * 2);
  unsigned short* wWiB  = take((size_t)512 * KWI * 2);
  unsigned short* wWhB  = take((size_t)512 * KWH * 2);
  unsigned short* wWoB  = take((size_t)512 * KWO * 2);
  unsigned short* wF1B  = take((size_t)NHID * 1024 * 2);

  zero_pads<<<512, 256, 0, stream>>>(wNei, wWoIn, wEnc);

  for (int side = 0; side < 2; ++side) {
    const float* f_atoms = (const float*)d_in[side * 10 + 0];
    const float* f_bonds = (const float*)d_in[side * 10 + 1];
    const int*   a2a     = (const int*)  d_in[side * 10 + 2];
    const int*   a2b     = (const int*)  d_in[side * 10 + 3];
    const float* Wi_w    = (const float*)d_in[side * 10 + 4];
    const float* Wi_b    = (const float*)d_in[side * 10 + 5];
    const float* Wh_w    = (const float*)d_in[side * 10 + 6];
    const float* Wh_b    = (const float*)d_in[side * 10 + 7];
    const float* Wo_w    = (const float*)d_in[side * 10 + 8];
    const float* Wo_b    = (const float*)d_in[side * 10 + 9];

    convw<<<(512 * KWI) / 256, 256, 0, stream>>>(wWiB, Wi_w, FATOM, KWI, 512, 0);
    convw<<<(512 * KWH) / 256, 256, 0, stream>>>(wWhB, Wh_w, 526, KWH, 512, 0);
    convw<<<(512 * KWO) / 256, 256, 0, stream>>>(wWoB, Wo_w, 645, KWO, 512, 1);
    atoms_prep<<<(A_PAD * KWI) / 256, 256, 0, stream>>>(wWoIn, f_atoms);
    bond_gather<<<(A_REAL + 255) / 256, 256, 0, stream>>>(wNei, f_bonds, a2b);

    // x = f_atoms @ Wi^T + b  (pre-relu; A read from wWoIn cols 512..671)
    gemm_bf16<0, 4><<<MT256 * 4, 512, 0, stream>>>(wWoIn + 512, KWO, wWiB, KWI,
                                                   Wi_b, KWI, wX, nullptr, HD);
    for (int it = 0; it < 3; ++it) {
      gather6<<<A_REAL / 4, 256, 0, stream>>>(wNei, KWH, it == 0 ? wX : wS, a2a);
      gemm_bf16<1, 4><<<MT256 * 4, 512, 0, stream>>>(wNei, KWH, wWhB, KWH,
                                                     Wh_b, KWH, wS, wX, HD);
    }
    gather6<<<A_REAL / 4, 256, 0, stream>>>(wWoIn, KWO, wS, a2a);
    gemm_bf16<2, 4><<<MT256 * 4, 512, 0, stream>>>(wWoIn, KWO, wWoB, KWO,
                                                   Wo_b, KWO, wH, nullptr, HD);
    readout<<<NMOL, 256, 0, stream>>>(wH, wEnc + side * HD);
  }

  const float* ffn1_w = (const float*)d_in[20];
  const float* ffn1_b = (const float*)d_in[21];
  const float* ffn2_w = (const float*)d_in[22];
  const float* ffn2_b = (const float*)d_in[23];

  convw<<<(NHID * 1024) / 256, 256, 0, stream>>>(wF1B, ffn1_w, 1024, 1024, NHID, 0);
  gemm_bf16<2, 2><<<16, 512, 0, stream>>>(wEnc, 1024, wF1B, 1024,
                                          ffn1_b, 1024, wFF1, nullptr, NHID);
  ffn2_red<<<NMOL, 256, 0, stream>>>(wFF1, ffn2_w, ffn2_b, (float*)d_out);
}

// Round 7
// 1051.808 us; speedup vs baseline: 1.7542x; 1.0068x over previous
//
#include <hip/hip_runtime.h>
#include <hip/hip_bf16.h>
#include <cstdint>
#include <cstddef>

#define A_REAL 50000
#define A_PAD  50176      // 196 * 256
#define MT256  196
#define PADROWS 176
#define NBOND  6
#define HD     512
#define FATOM  133
#define FBOND  14
#define KWI    160        // 133 padded to mult of 32
#define KWH    544        // 512+14 padded
#define KU     704        // unified row: nei(512) | bond(32) | f_atoms(160)
#define NMOL   2000
#define MOLPAD 2048
#define APM    25
#define NHID   256

typedef __bf16 bf16x8 __attribute__((ext_vector_type(8)));
typedef float  f32x4  __attribute__((ext_vector_type(4)));
typedef short  short8 __attribute__((ext_vector_type(8)));
typedef short  short4v __attribute__((ext_vector_type(4)));

__device__ __forceinline__ float b2f(unsigned short u) {
  return __uint_as_float(((unsigned int)u) << 16);
}
__device__ __forceinline__ unsigned short f2b(float f) {
  unsigned int x = __float_as_uint(f);
  unsigned int r = (x + 0x7fffu + ((x >> 16) & 1u)) >> 16;
  return (unsigned short)r;
}

// ---------------- zero pad rows of wU (all allocated slots) + wEnc pad -------
__global__ void zero_pads(unsigned short* __restrict__ wU, unsigned long long sU,
                          int nsAlloc, unsigned short* __restrict__ wEnc)
{
  const int t = blockIdx.x * 256 + threadIdx.x;
  if (t < PADROWS * KU) {
    for (int s = 0; s < nsAlloc; ++s)
      wU[s * sU + (size_t)A_REAL * KU + t] = 0;
  }
  if (t < 48 * 1024) wEnc[(size_t)NMOL * 1024 + t] = 0;
}

// ---------------- f32 weights -> padded bf16 ---------------------------------
// mode 0: plain pad to ldd.  mode 1: Wo -> 704 layout: cols 0..511 = a_msg part
// (src col 133+k), 512..543 = 0 (bond slot, weight zero), 544..676 = f_atoms
// part (src col k-544), rest 0.
__global__ void convw(unsigned short* __restrict__ dst, const float* __restrict__ src,
                      int Ksrc, int ldd, int rows, int mode)
{
  const int idx = blockIdx.x * 256 + threadIdx.x;
  if (idx >= rows * ldd) return;
  const int n = idx / ldd, k = idx % ldd;
  float v = 0.f;
  if (mode == 0) {
    if (k < Ksrc) v = src[(size_t)n * Ksrc + k];
  } else {
    if (k < 512)                  v = src[(size_t)n * 645 + 133 + k];
    else if (k >= 544 && k < 677) v = src[(size_t)n * 645 + (k - 544)];
  }
  dst[(size_t)n * ldd + k] = f2b(v);
}

// ---------------- f_atoms -> wU cols 544..703 (bf16, padded) -----------------
__global__ void atoms_prep(unsigned short* __restrict__ wU, const float* __restrict__ f_atoms)
{
  const int idx = blockIdx.x * 256 + threadIdx.x;
  if (idx >= A_PAD * 160) return;
  const int r = idx / 160, c = idx % 160;
  float v = 0.f;
  if (r < A_REAL && c < FATOM) v = f_atoms[(size_t)r * FATOM + c];
  wU[(size_t)r * KU + 544 + c] = f2b(v);
}

// ---------------- bond gather-sum -> wU cols 512..543 (once per side) --------
__global__ void bond_gather(unsigned short* __restrict__ wU, const float* __restrict__ f_bonds,
                            const int* __restrict__ a2b)
{
  const int a = blockIdx.x * 256 + threadIdx.x;
  if (a >= A_REAL) return;
  float acc[FBOND];
  #pragma unroll
  for (int c = 0; c < FBOND; ++c) acc[c] = 0.f;
  #pragma unroll
  for (int j = 0; j < NBOND; ++j) {
    const int b = a2b[a * NBOND + j];
    const float* row = f_bonds + (size_t)b * FBOND;
    #pragma unroll
    for (int c = 0; c < FBOND; ++c) acc[c] += row[c];
  }
  unsigned short* d = wU + (size_t)a * KU + 512;
  #pragma unroll
  for (int c = 0; c < FBOND; ++c) d[c] = f2b(acc[c]);
  #pragma unroll
  for (int c = FBOND; c < 32; ++c) d[c] = 0;
}

// ------- 6-neighbor gather-sum of relu(state) -> wU cols 0..511, dual-side ---
// relu applied here (relu(bf16(s)) == bf16(relu(s))) so GEMMs store
// pre-activation state.
__launch_bounds__(256)
__global__ void gather6(unsigned short* __restrict__ dst, unsigned long long sDst,
                        const unsigned short* __restrict__ st, unsigned long long sSt,
                        const int* __restrict__ a2aA, const int* __restrict__ a2aB,
                        int bps)
{
  const int blk  = blockIdx.x;
  const int side = blk / bps;
  const int lb   = blk - side * bps;
  const int* a2a = side ? a2aB : a2aA;
  unsigned short* d = dst + side * sDst;
  const unsigned short* state = st + side * sSt;

  const int a    = lb * 4 + (threadIdx.x >> 6);
  const int lane = threadIdx.x & 63;
  const int* idx = a2a + a * NBOND;
  float acc[8] = {0.f,0.f,0.f,0.f,0.f,0.f,0.f,0.f};
  #pragma unroll
  for (int j = 0; j < NBOND; ++j) {
    const int r = idx[j];
    short8 v = *reinterpret_cast<const short8*>(state + (size_t)r * HD + lane * 8);
    #pragma unroll
    for (int e = 0; e < 8; ++e) acc[e] += fmaxf(b2f((unsigned short)v[e]), 0.f);
  }
  short8 o;
  #pragma unroll
  for (int e = 0; e < 8; ++e) o[e] = (short)f2b(acc[e]);
  *reinterpret_cast<short8*>(d + (size_t)a * KU + lane * 8) = o;
}

// ---------------- bf16 MFMA GEMM, 256x128 tile, depth-2 prefetch, dual-side --
// C[M x N] = A[M x K] * W[N x K]^T  (bf16 in, fp32 accum)
// 8 waves/512thr, LDS ring 3x24KB, counted vmcnt(3) (stage = 2xA + 1xB 16B
// loads/thread); stage(t+2) issued mid-compute. Bijective XCD swizzle over the
// FULL merged grid; side = gid / blocksPerSide (both sides run in one
// dispatch: 2x parallelism, half the serialization drains).
// OPERAND-SWAPPED MFMA: lane = M-row, 4 acc regs = 4 consecutive N cols ->
// 8B coalesced epilogue stores.
// MODE 0 (Wi): outA = acc + bias              (x, pre-relu state)
// MODE 1 (Wh): outA = acc + bias + outB(=x)   (pre-relu state; relu in gather)
// MODE 2 (Wo/FFN1): outA = relu(acc + bias)
struct GemmP {
  const unsigned short* A; unsigned long long sA; int lda;
  const unsigned short* W; unsigned long long sW; int ldb;
  const float* bias0; const float* bias1;
  unsigned short* outA; unsigned long long sOutA;
  const unsigned short* outB; unsigned long long sOutB;
  int outLd; int K; int bps;
};

template<int MODE, int NTN>
__launch_bounds__(512, 4)
__global__ void gemm_bf16(GemmP p)
{
  __shared__ alignas(16) unsigned short lA[3][256 * 32];
  __shared__ alignas(16) unsigned short lB[3][128 * 32];
  const int tid  = threadIdx.x;
  const int lane = tid & 63;
  const int wav  = tid >> 6;
  const int wm = wav >> 1, wn = wav & 1;

  // bijective chunked XCD swizzle (m204)
  const int nwg = gridDim.x;
  const int id  = blockIdx.x;
  const int q = nwg >> 3, r = nwg & 7;
  const int xcd = id & 7, jj = id >> 3;
  const int gid = (xcd < r ? xcd * (q + 1) : r * (q + 1) + (xcd - r) * q) + jj;
  const int side = gid / p.bps;
  const int lid  = gid - side * p.bps;
  const int bxt = lid / NTN;
  const int byt = lid - bxt * NTN;
  const size_t tileM = (size_t)bxt * 256;
  const int n0 = byt * 128;

  const float* bias = side ? p.bias1 : p.bias0;
  const unsigned short* Aside = p.A + side * p.sA;
  const unsigned short* Wside = p.W + side * p.sW;
  unsigned short* outA = p.outA + side * p.sOutA;

  const int srow = tid >> 2;           // staging row (0..127) within a pass
  const int scol = (tid & 3) * 8;      // staging col (bf16) within 32
  const int fr = lane & 15;
  const int fk = (lane >> 4) * 8;

  f32x4 acc[4][4];
  #pragma unroll
  for (int m = 0; m < 4; ++m)
    #pragma unroll
    for (int n = 0; n < 4; ++n)
      acc[m][n] = (f32x4){0.f, 0.f, 0.f, 0.f};

  const unsigned short* Abase = Aside + tileM * (size_t)p.lda;
  const unsigned short* Wbase = Wside + (size_t)n0 * (size_t)p.ldb;
  const int lda = p.lda, ldb = p.ldb;
  const int nt = p.K >> 5;

  auto stage = [&](int t, int buf) {
    const int k0 = t * 32;
    #pragma unroll
    for (int i = 0; i < 2; ++i) {
      const int rr = i * 128 + srow;
      const unsigned short* ga = Abase + (size_t)rr * lda + (k0 + scol);
      __builtin_amdgcn_global_load_lds(
          (const __attribute__((address_space(1))) unsigned int*)ga,
          (__attribute__((address_space(3))) unsigned int*)&lA[buf][rr * 32 + scol], 16, 0, 0);
    }
    const unsigned short* gb = Wbase + (size_t)srow * ldb + (k0 + scol);
    __builtin_amdgcn_global_load_lds(
        (const __attribute__((address_space(1))) unsigned int*)gb,
        (__attribute__((address_space(3))) unsigned int*)&lB[buf][srow * 32 + scol], 16, 0, 0);
  };

  stage(0, 0);
  if (nt > 1) stage(1, 1);

  int buf = 0;
  for (int t = 0; t < nt; ++t) {
    if (t + 1 < nt) asm volatile("s_waitcnt vmcnt(3)" ::: "memory");
    else            asm volatile("s_waitcnt vmcnt(0)" ::: "memory");
    __builtin_amdgcn_s_barrier();
    asm volatile("" ::: "memory");

    bf16x8 af[4], bfm[4];
    #pragma unroll
    for (int m = 0; m < 4; ++m)
      af[m] = *reinterpret_cast<const bf16x8*>(&lA[buf][(wm * 64 + m * 16 + fr) * 32 + fk]);
    #pragma unroll
    for (int n = 0; n < 4; ++n)
      bfm[n] = *reinterpret_cast<const bf16x8*>(&lB[buf][(wn * 64 + n * 16 + fr) * 32 + fk]);

    if (t + 2 < nt) {
      int b2v = buf + 2; if (b2v >= 3) b2v -= 3;
      stage(t + 2, b2v);
    }

    // operand-swapped: acc[m][n] reg i, lane l =
    //   C[tileM + wm*64 + m*16 + (l&15)][n0 + wn*64 + n*16 + (l>>4)*4 + i]
    #pragma unroll
    for (int m = 0; m < 4; ++m)
      #pragma unroll
      for (int n = 0; n < 4; ++n)
        acc[m][n] = __builtin_amdgcn_mfma_f32_16x16x32_bf16(bfm[n], af[m], acc[m][n], 0, 0, 0);

    buf = (buf == 2) ? 0 : buf + 1;
  }

  const int erow = lane & 15;
  const int ecol = (lane >> 4) * 4;
  #pragma unroll
  for (int m = 0; m < 4; ++m) {
    const size_t rowg = tileM + wm * 64 + m * 16 + erow;
    #pragma unroll
    for (int n = 0; n < 4; ++n) {
      const int colg = n0 + wn * 64 + n * 16 + ecol;
      const f32x4 bv = *reinterpret_cast<const f32x4*>(&bias[colg]);
      const size_t off = rowg * (size_t)p.outLd + colg;
      float v[4];
      #pragma unroll
      for (int e = 0; e < 4; ++e) v[e] = acc[m][n][e] + bv[e];
      short4v o;
      if (MODE == 0) {
        #pragma unroll
        for (int e = 0; e < 4; ++e) o[e] = (short)f2b(v[e]);
      } else if (MODE == 1) {
        const unsigned short* outB = p.outB + side * p.sOutB;
        const short4v xv = *reinterpret_cast<const short4v*>(&outB[off]);
        #pragma unroll
        for (int e = 0; e < 4; ++e) o[e] = (short)f2b(v[e] + b2f((unsigned short)xv[e]));
      } else {
        #pragma unroll
        for (int e = 0; e < 4; ++e) o[e] = (short)f2b(fmaxf(v[e], 0.f));
      }
      *reinterpret_cast<short4v*>(&outA[off]) = o;
    }
  }
}

// ---------------- per-molecule mean over 25 atoms -> enc (bf16), dual-side ---
__launch_bounds__(256)
__global__ void readout(const unsigned short* __restrict__ h, unsigned long long sH,
                        unsigned short* __restrict__ enc, int sideBase, int bps)
{
  const int blk = blockIdx.x;
  const int s   = blk / bps;
  const int mol = blk - s * bps;
  const int t = threadIdx.x;               // cols 2t, 2t+1
  const unsigned short* base = h + s * sH + (size_t)mol * APM * HD + t * 2;
  float s0 = 0.f, s1 = 0.f;
  #pragma unroll
  for (int r = 0; r < APM; ++r) {
    unsigned int v = *reinterpret_cast<const unsigned int*>(base + (size_t)r * HD);
    s0 += b2f((unsigned short)(v & 0xffffu));
    s1 += b2f((unsigned short)(v >> 16));
  }
  s0 *= (1.f / 25.f);
  s1 *= (1.f / 25.f);
  unsigned int o = (unsigned int)f2b(s0) | ((unsigned int)f2b(s1) << 16);
  const int colOff = (sideBase + s) * HD;
  *reinterpret_cast<unsigned int*>(enc + (size_t)mol * 1024 + colOff + t * 2) = o;
}

// ---------------- final dot with ffn2 ----------------------------------------
__launch_bounds__(256)
__global__ void ffn2_red(const unsigned short* __restrict__ ff1, const float* __restrict__ w2,
                         const float* __restrict__ b2, float* __restrict__ out)
{
  __shared__ float red[256];
  const int mol = blockIdx.x, t = threadIdx.x;
  red[t] = b2f(ff1[(size_t)mol * NHID + t]) * w2[t];
  __syncthreads();
  #pragma unroll
  for (int s = 128; s > 0; s >>= 1) {
    if (t < s) red[t] += red[t + s];
    __syncthreads();
  }
  if (t == 0) out[mol] = red[0] + b2[0];
}

// -----------------------------------------------------------------------------
extern "C" void kernel_launch(void* const* d_in, const int* in_sizes, int n_in,
                              void* d_out, int out_size, void* d_ws, size_t ws_size,
                              hipStream_t stream)
{
  (void)in_sizes; (void)n_in; (void)out_size;

  // NS=2: both sides resident (one merged pipeline). Needs ~356 MB of ws.
  const int NS = (ws_size >= 365ull * 1024 * 1024) ? 2 : 1;

  unsigned char* p = (unsigned char*)d_ws;
  auto take = [&](size_t bytes) -> unsigned short* {
    unsigned short* r = (unsigned short*)p;
    p += (bytes + 1023) & ~(size_t)1023;
    return r;
  };
  const unsigned long long sX = (unsigned long long)A_PAD * HD;   // elems
  const unsigned long long sU = (unsigned long long)A_PAD * KU;
  unsigned short* wX   = take((size_t)NS * sX * 2);   // x / later h
  unsigned short* wS   = take((size_t)NS * sX * 2);   // pre-relu state s
  unsigned short* wU   = take((size_t)NS * sU * 2);   // [nei|bond|f_atoms]
  unsigned short* wEnc = take((size_t)MOLPAD * 1024 * 2);
  unsigned short* wFF1 = take((size_t)MOLPAD * NHID * 2);
  unsigned short* wWiB = take((size_t)NS * 512 * KWI * 2);
  unsigned short* wWhB = take((size_t)NS * 512 * KWH * 2);
  unsigned short* wWoB = take((size_t)NS * 512 * KU  * 2);
  unsigned short* wF1B = take((size_t)NHID * 1024 * 2);

  const float* biasWi[2]; const float* biasWh[2]; const float* biasWo[2];
  const int* a2aP[2];
  for (int s = 0; s < 2; ++s) {
    biasWi[s] = (const float*)d_in[s * 10 + 5];
    biasWh[s] = (const float*)d_in[s * 10 + 7];
    biasWo[s] = (const float*)d_in[s * 10 + 9];
    a2aP[s]   = (const int*)  d_in[s * 10 + 2];
  }

  zero_pads<<<484, 256, 0, stream>>>(wU, sU, NS, wEnc);

  auto prep = [&](int side, int slot) {
    const float* f_atoms = (const float*)d_in[side * 10 + 0];
    const float* f_bonds = (const float*)d_in[side * 10 + 1];
    const int*   a2b     = (const int*)  d_in[side * 10 + 3];
    const float* Wi_w    = (const float*)d_in[side * 10 + 4];
    const float* Wh_w    = (const float*)d_in[side * 10 + 6];
    const float* Wo_w    = (const float*)d_in[side * 10 + 8];
    convw<<<(512 * KWI) / 256, 256, 0, stream>>>(wWiB + slot * 512 * KWI, Wi_w, FATOM, KWI, 512, 0);
    convw<<<(512 * KWH) / 256, 256, 0, stream>>>(wWhB + slot * 512 * KWH, Wh_w, 526, KWH, 512, 0);
    convw<<<(512 * KU)  / 256, 256, 0, stream>>>(wWoB + slot * 512 * KU,  Wo_w, 645, KU,  512, 1);
    atoms_prep<<<(A_PAD * 160) / 256, 256, 0, stream>>>(wU + slot * sU, f_atoms);
    bond_gather<<<(A_REAL + 255) / 256, 256, 0, stream>>>(wU + slot * sU, f_bonds, a2b);
  };

  auto mp = [&](int sb, int ns) {
    const int BPS = MT256 * 4;           // 784 blocks per side
    GemmP g;
    // Wi: x = f_atoms @ Wi^T + b   (A = wU cols 544.., K=160)
    g = { wU + 544, sU, KU, wWiB, 512ull * KWI, KWI,
          biasWi[sb], biasWi[sb + ns - 1],
          wX, sX, nullptr, 0, HD, KWI, BPS };
    gemm_bf16<0, 4><<<ns * BPS, 512, 0, stream>>>(g);
    for (int it = 0; it < 3; ++it) {
      gather6<<<ns * (A_REAL / 4), 256, 0, stream>>>(
          wU, sU, it == 0 ? wX : wS, sX,
          a2aP[sb], a2aP[sb + ns - 1], A_REAL / 4);
      g = { wU, sU, KU, wWhB, 512ull * KWH, KWH,
            biasWh[sb], biasWh[sb + ns - 1],
            wS, sX, wX, sX, HD, KWH, BPS };
      gemm_bf16<1, 4><<<ns * BPS, 512, 0, stream>>>(g);
    }
    gather6<<<ns * (A_REAL / 4), 256, 0, stream>>>(
        wU, sU, wS, sX, a2aP[sb], a2aP[sb + ns - 1], A_REAL / 4);
    // Wo: h = relu(...) -> reuse wX (x dead after last Wh)
    g = { wU, sU, KU, wWoB, 512ull * KU, KU,
          biasWo[sb], biasWo[sb + ns - 1],
          wX, sX, nullptr, 0, HD, KU, BPS };
    gemm_bf16<2, 4><<<ns * BPS, 512, 0, stream>>>(g);
    readout<<<ns * NMOL, 256, 0, stream>>>(wX, sX, wEnc, sb, NMOL);
  };

  if (NS == 2) {
    prep(0, 0); prep(1, 1);
    mp(0, 2);
  } else {
    prep(0, 0); mp(0, 1);
    prep(1, 0); mp(1, 1);
  }

  const float* ffn1_w = (const float*)d_in[20];
  const float* ffn1_b = (const float*)d_in[21];
  const float* ffn2_w = (const float*)d_in[22];
  const float* ffn2_b = (const float*)d_in[23];

  convw<<<(NHID * 1024) / 256, 256, 0, stream>>>(wF1B, ffn1_w, 1024, 1024, NHID, 0);
  GemmP gf = { wEnc, 0, 1024, wF1B, 0, 1024,
               ffn1_b, ffn1_b, wFF1, 0, nullptr, 0, NHID, 1024, 16 };
  gemm_bf16<2, 2><<<16, 512, 0, stream>>>(gf);
  ffn2_red<<<NMOL, 256, 0, stream>>>(wFF1, ffn2_w, ffn2_b, (float*)d_out);
}

// Round 9
// 990.353 us; speedup vs baseline: 1.8630x; 1.0621x over previous
//
#include <hip/hip_runtime.h>
#include <hip/hip_bf16.h>
#include <cstdint>
#include <cstddef>

#define A_REAL 50000
#define A_PAD  50176      // 196 * 256
#define MT256  196
#define PADROWS 176
#define NBOND  6
#define HD     512
#define FATOM  133
#define FBOND  14
#define KWI    160        // f_atoms block width (133 padded)
#define KU     704        // unified row: nei(512) | bond(32) | f_atoms(160)
#define NMOL   2000
#define MOLPAD 2048
#define APM    25
#define NHID   256

typedef __bf16 bf16x8 __attribute__((ext_vector_type(8)));
typedef float  f32x4  __attribute__((ext_vector_type(4)));
typedef short  short8 __attribute__((ext_vector_type(8)));
typedef short  short4v __attribute__((ext_vector_type(4)));

__device__ __forceinline__ float b2f(unsigned short u) {
  return __uint_as_float(((unsigned int)u) << 16);
}
__device__ __forceinline__ unsigned short f2b(float f) {
  unsigned int x = __float_as_uint(f);
  unsigned int r = (x + 0x7fffu + ((x >> 16) & 1u)) >> 16;
  return (unsigned short)r;
}
// fp16 state (s, h, ff1): 8x finer rounding than bf16, same 2B footprint.
__device__ __forceinline__ unsigned short f2h(float f) {
  _Float16 h = (_Float16)f;                 // v_cvt_f16_f32, RNE
  return *(unsigned short*)&h;
}
__device__ __forceinline__ float h2f(unsigned short u) {
  _Float16 h = *(_Float16*)&u;
  return (float)h;
}

// ---------------- zero pad rows of wU (all allocated slots) + wEnc pad -------
__global__ void zero_pads(unsigned short* __restrict__ wU, unsigned long long sU,
                          int nsAlloc, unsigned short* __restrict__ wEnc)
{
  const int t = blockIdx.x * 256 + threadIdx.x;
  if (t < PADROWS * KU) {
    for (int s = 0; s < nsAlloc; ++s)
      wU[s * sU + (size_t)A_REAL * KU + t] = 0;
  }
  if (t < 48 * 1024) wEnc[(size_t)NMOL * 1024 + t] = 0;
}

// ---------------- f32 weights -> padded bf16 ---------------------------------
// mode 0: plain pad to ldd (Wi [512][133] -> [512][KWI], FFN1 [256][1024]).
// mode 1: Wo [512][645]=[f_atoms|a_msg] -> KU layout:
//         k<512 = a_msg part (src 133+k), 512..543 = 0, 544..676 = f_atoms.
// mode 2: Wh+Wi combined -> KU layout:
//         k<526 = Wh (src k; 512 nei + 14 bond), 526..543 = 0,
//         544..676 = Wi (srcB k-544).
__global__ void convw(unsigned short* __restrict__ dst, const float* __restrict__ src,
                      const float* __restrict__ srcB,
                      int Ksrc, int ldd, int rows, int mode)
{
  const int idx = blockIdx.x * 256 + threadIdx.x;
  if (idx >= rows * ldd) return;
  const int n = idx / ldd, k = idx % ldd;
  float v = 0.f;
  if (mode == 0) {
    if (k < Ksrc) v = src[(size_t)n * Ksrc + k];
  } else if (mode == 1) {
    if (k < 512)                  v = src[(size_t)n * 645 + 133 + k];
    else if (k >= 544 && k < 677) v = src[(size_t)n * 645 + (k - 544)];
  } else {
    if (k < 526)                  v = src[(size_t)n * 526 + k];
    else if (k >= 544 && k < 677) v = srcB[(size_t)n * 133 + (k - 544)];
  }
  dst[(size_t)n * ldd + k] = f2b(v);
}

// ---------------- combined bias bh + bi (f32) --------------------------------
__global__ void bias_comb(float* __restrict__ dst, const float* __restrict__ bh,
                          const float* __restrict__ bi)
{
  const int t = blockIdx.x * 256 + threadIdx.x;
  if (t < HD) dst[t] = bh[t] + bi[t];
}

// ---------------- f_atoms -> wU cols 544..703 (bf16, padded) -----------------
__global__ void atoms_prep(unsigned short* __restrict__ wU, const float* __restrict__ f_atoms)
{
  const int idx = blockIdx.x * 256 + threadIdx.x;
  if (idx >= A_PAD * KWI) return;
  const int r = idx / KWI, c = idx % KWI;
  float v = 0.f;
  if (r < A_REAL && c < FATOM) v = f_atoms[(size_t)r * FATOM + c];
  wU[(size_t)r * KU + 544 + c] = f2b(v);
}

// ---------------- bond gather-sum -> wU cols 512..543 (once per side) --------
__global__ void bond_gather(unsigned short* __restrict__ wU, const float* __restrict__ f_bonds,
                            const int* __restrict__ a2b)
{
  const int a = blockIdx.x * 256 + threadIdx.x;
  if (a >= A_REAL) return;
  float acc[FBOND];
  #pragma unroll
  for (int c = 0; c < FBOND; ++c) acc[c] = 0.f;
  #pragma unroll
  for (int j = 0; j < NBOND; ++j) {
    const int b = a2b[a * NBOND + j];
    const float* row = f_bonds + (size_t)b * FBOND;
    #pragma unroll
    for (int c = 0; c < FBOND; ++c) acc[c] += row[c];
  }
  unsigned short* d = wU + (size_t)a * KU + 512;
  #pragma unroll
  for (int c = 0; c < FBOND; ++c) d[c] = f2b(acc[c]);
  #pragma unroll
  for (int c = FBOND; c < 32; ++c) d[c] = 0;
}

// ------- 6-neighbor gather-sum of relu(fp16 state) -> wU cols 0..511 ---------
// state is fp16 (fine rounding); nei output must be bf16 (MFMA A operand).
__launch_bounds__(256)
__global__ void gather6(unsigned short* __restrict__ dst, unsigned long long sDst,
                        const unsigned short* __restrict__ st, unsigned long long sSt,
                        const int* __restrict__ a2aA, const int* __restrict__ a2aB,
                        int bps)
{
  const int blk  = blockIdx.x;
  const int side = blk / bps;
  const int lb   = blk - side * bps;
  const int* a2a = side ? a2aB : a2aA;
  unsigned short* d = dst + side * sDst;
  const unsigned short* state = st + side * sSt;

  const int a    = lb * 4 + (threadIdx.x >> 6);
  const int lane = threadIdx.x & 63;
  const int* idx = a2a + a * NBOND;
  float acc[8] = {0.f,0.f,0.f,0.f,0.f,0.f,0.f,0.f};
  #pragma unroll
  for (int j = 0; j < NBOND; ++j) {
    const int r = idx[j];
    short8 v = *reinterpret_cast<const short8*>(state + (size_t)r * HD + lane * 8);
    #pragma unroll
    for (int e = 0; e < 8; ++e) acc[e] += fmaxf(h2f((unsigned short)v[e]), 0.f);
  }
  short8 o;
  #pragma unroll
  for (int e = 0; e < 8; ++e) o[e] = (short)f2b(acc[e]);
  *reinterpret_cast<short8*>(d + (size_t)a * KU + lane * 8) = o;
}

// ---------------- bf16 MFMA GEMM, 256x128 tile, depth-2 prefetch, dual-side --
// C[M x N] = A[M x K] * W[N x K]^T  (bf16 in, fp32 accum, fp16 out)
// 8 waves/512thr, LDS ring 3x24KB, counted vmcnt(3); stage(t+2) mid-compute.
// Bijective XCD swizzle over full merged grid; side = gid / bps.
// x-FOLD: Wi folded into Wh (K=704 over [nei|bond|f_atoms], bias bh+bi);
// no x tensor. Output state/h/ff1 stored FP16 (8x finer than bf16) to keep
// absmax under threshold (r8 failed at bf16 by 3%).
// OPERAND-SWAPPED MFMA: lane = M-row, 4 acc regs = 4 consecutive N cols.
// MODE 0: out = fp16(acc + bias)         (pre-relu state; relu in gather)
// MODE 2: out = fp16(relu(acc + bias))   (Wo / FFN1)
struct GemmP {
  const unsigned short* A; unsigned long long sA; int lda;
  const unsigned short* W; unsigned long long sW; int ldb;
  const float* bias0; const float* bias1;
  unsigned short* outA; unsigned long long sOutA;
  int outLd; int K; int bps;
};

template<int MODE, int NTN>
__launch_bounds__(512, 4)
__global__ void gemm_bf16(GemmP p)
{
  __shared__ alignas(16) unsigned short lA[3][256 * 32];
  __shared__ alignas(16) unsigned short lB[3][128 * 32];
  const int tid  = threadIdx.x;
  const int lane = tid & 63;
  const int wav  = tid >> 6;
  const int wm = wav >> 1, wn = wav & 1;

  // bijective chunked XCD swizzle (m204)
  const int nwg = gridDim.x;
  const int id  = blockIdx.x;
  const int q = nwg >> 3, r = nwg & 7;
  const int xcd = id & 7, jj = id >> 3;
  const int gid = (xcd < r ? xcd * (q + 1) : r * (q + 1) + (xcd - r) * q) + jj;
  const int side = gid / p.bps;
  const int lid  = gid - side * p.bps;
  const int bxt = lid / NTN;
  const int byt = lid - bxt * NTN;
  const size_t tileM = (size_t)bxt * 256;
  const int n0 = byt * 128;

  const float* bias = side ? p.bias1 : p.bias0;
  const unsigned short* Aside = p.A + side * p.sA;
  const unsigned short* Wside = p.W + side * p.sW;
  unsigned short* outA = p.outA + side * p.sOutA;

  const int srow = tid >> 2;           // staging row (0..127) within a pass
  const int scol = (tid & 3) * 8;      // staging col (bf16) within 32
  const int fr = lane & 15;
  const int fk = (lane >> 4) * 8;

  f32x4 acc[4][4];
  #pragma unroll
  for (int m = 0; m < 4; ++m)
    #pragma unroll
    for (int n = 0; n < 4; ++n)
      acc[m][n] = (f32x4){0.f, 0.f, 0.f, 0.f};

  const unsigned short* Abase = Aside + tileM * (size_t)p.lda;
  const unsigned short* Wbase = Wside + (size_t)n0 * (size_t)p.ldb;
  const int lda = p.lda, ldb = p.ldb;
  const int nt = p.K >> 5;

  auto stage = [&](int t, int buf) {
    const int k0 = t * 32;
    #pragma unroll
    for (int i = 0; i < 2; ++i) {
      const int rr = i * 128 + srow;
      const unsigned short* ga = Abase + (size_t)rr * lda + (k0 + scol);
      __builtin_amdgcn_global_load_lds(
          (const __attribute__((address_space(1))) unsigned int*)ga,
          (__attribute__((address_space(3))) unsigned int*)&lA[buf][rr * 32 + scol], 16, 0, 0);
    }
    const unsigned short* gb = Wbase + (size_t)srow * ldb + (k0 + scol);
    __builtin_amdgcn_global_load_lds(
        (const __attribute__((address_space(1))) unsigned int*)gb,
        (__attribute__((address_space(3))) unsigned int*)&lB[buf][srow * 32 + scol], 16, 0, 0);
  };

  stage(0, 0);
  if (nt > 1) stage(1, 1);

  int buf = 0;
  for (int t = 0; t < nt; ++t) {
    if (t + 1 < nt) asm volatile("s_waitcnt vmcnt(3)" ::: "memory");
    else            asm volatile("s_waitcnt vmcnt(0)" ::: "memory");
    __builtin_amdgcn_s_barrier();
    asm volatile("" ::: "memory");

    bf16x8 af[4], bfm[4];
    #pragma unroll
    for (int m = 0; m < 4; ++m)
      af[m] = *reinterpret_cast<const bf16x8*>(&lA[buf][(wm * 64 + m * 16 + fr) * 32 + fk]);
    #pragma unroll
    for (int n = 0; n < 4; ++n)
      bfm[n] = *reinterpret_cast<const bf16x8*>(&lB[buf][(wn * 64 + n * 16 + fr) * 32 + fk]);

    if (t + 2 < nt) {
      int b2v = buf + 2; if (b2v >= 3) b2v -= 3;
      stage(t + 2, b2v);
    }

    // operand-swapped: acc[m][n] reg i, lane l =
    //   C[tileM + wm*64 + m*16 + (l&15)][n0 + wn*64 + n*16 + (l>>4)*4 + i]
    #pragma unroll
    for (int m = 0; m < 4; ++m)
      #pragma unroll
      for (int n = 0; n < 4; ++n)
        acc[m][n] = __builtin_amdgcn_mfma_f32_16x16x32_bf16(bfm[n], af[m], acc[m][n], 0, 0, 0);

    buf = (buf == 2) ? 0 : buf + 1;
  }

  const int erow = lane & 15;
  const int ecol = (lane >> 4) * 4;
  #pragma unroll
  for (int m = 0; m < 4; ++m) {
    const size_t rowg = tileM + wm * 64 + m * 16 + erow;
    #pragma unroll
    for (int n = 0; n < 4; ++n) {
      const int colg = n0 + wn * 64 + n * 16 + ecol;
      const f32x4 bv = *reinterpret_cast<const f32x4*>(&bias[colg]);
      const size_t off = rowg * (size_t)p.outLd + colg;
      float v[4];
      #pragma unroll
      for (int e = 0; e < 4; ++e) v[e] = acc[m][n][e] + bv[e];
      short4v o;
      if (MODE == 0) {
        #pragma unroll
        for (int e = 0; e < 4; ++e) o[e] = (short)f2h(v[e]);
      } else {
        #pragma unroll
        for (int e = 0; e < 4; ++e) o[e] = (short)f2h(fmaxf(v[e], 0.f));
      }
      *reinterpret_cast<short4v*>(&outA[off]) = o;
    }
  }
}

// ---------------- per-molecule mean over 25 atoms -> enc (bf16), dual-side ---
__launch_bounds__(256)
__global__ void readout(const unsigned short* __restrict__ h, unsigned long long sH,
                        unsigned short* __restrict__ enc, int sideBase, int bps)
{
  const int blk = blockIdx.x;
  const int s   = blk / bps;
  const int mol = blk - s * bps;
  const int t = threadIdx.x;
  const unsigned short* base = h + s * sH + (size_t)mol * APM * HD + t * 2;
  float s0 = 0.f, s1 = 0.f;
  #pragma unroll
  for (int r = 0; r < APM; ++r) {
    unsigned int v = *reinterpret_cast<const unsigned int*>(base + (size_t)r * HD);
    s0 += h2f((unsigned short)(v & 0xffffu));
    s1 += h2f((unsigned short)(v >> 16));
  }
  s0 *= (1.f / 25.f);
  s1 *= (1.f / 25.f);
  unsigned int o = (unsigned int)f2b(s0) | ((unsigned int)f2b(s1) << 16);
  const int colOff = (sideBase + s) * HD;
  *reinterpret_cast<unsigned int*>(enc + (size_t)mol * 1024 + colOff + t * 2) = o;
}

// ---------------- final dot with ffn2 (ff1 is fp16) --------------------------
__launch_bounds__(256)
__global__ void ffn2_red(const unsigned short* __restrict__ ff1, const float* __restrict__ w2,
                         const float* __restrict__ b2, float* __restrict__ out)
{
  __shared__ float red[256];
  const int mol = blockIdx.x, t = threadIdx.x;
  red[t] = h2f(ff1[(size_t)mol * NHID + t]) * w2[t];
  __syncthreads();
  #pragma unroll
  for (int s = 128; s > 0; s >>= 1) {
    if (t < s) red[t] += red[t + s];
    __syncthreads();
  }
  if (t == 0) out[mol] = red[0] + b2[0];
}

// -----------------------------------------------------------------------------
extern "C" void kernel_launch(void* const* d_in, const int* in_sizes, int n_in,
                              void* d_out, int out_size, void* d_ws, size_t ws_size,
                              hipStream_t stream)
{
  (void)in_sizes; (void)n_in; (void)out_size;

  // NS=2 (both sides in one pipeline) needs ~253.05 MB after the x-fold.
  const int NS = (ws_size >= 253100000ull) ? 2 : 1;

  unsigned char* p = (unsigned char*)d_ws;
  auto take = [&](size_t bytes) -> unsigned short* {
    unsigned short* r = (unsigned short*)p;
    p += (bytes + 1023) & ~(size_t)1023;
    return r;
  };
  const unsigned long long sX = (unsigned long long)A_PAD * HD;   // elems
  const unsigned long long sU = (unsigned long long)A_PAD * KU;
  unsigned short* wS   = take((size_t)NS * sX * 2);   // fp16 state s / h
  unsigned short* wU   = take((size_t)NS * sU * 2);   // bf16 [nei|bond|f_atoms]
  unsigned short* wEnc = take((size_t)MOLPAD * 1024 * 2);   // bf16
  unsigned short* wFF1 = take((size_t)MOLPAD * NHID * 2);   // fp16
  unsigned short* wWiB = take((size_t)NS * 512 * KWI * 2);
  unsigned short* wWhC = take((size_t)NS * 512 * KU * 2);   // [Wh|0|Wi]
  unsigned short* wWoB = take((size_t)NS * 512 * KU * 2);
  unsigned short* wF1B = take((size_t)NHID * 1024 * 2);
  float*          wBC  = (float*)take((size_t)NS * HD * 4); // bh+bi

  const float* biasWi[2]; const float* biasWo[2];
  const int* a2aP[2];
  for (int s = 0; s < 2; ++s) {
    biasWi[s] = (const float*)d_in[s * 10 + 5];
    biasWo[s] = (const float*)d_in[s * 10 + 9];
    a2aP[s]   = (const int*)  d_in[s * 10 + 2];
  }

  zero_pads<<<484, 256, 0, stream>>>(wU, sU, NS, wEnc);

  auto prep = [&](int side, int slot) {
    const float* f_atoms = (const float*)d_in[side * 10 + 0];
    const float* f_bonds = (const float*)d_in[side * 10 + 1];
    const int*   a2b     = (const int*)  d_in[side * 10 + 3];
    const float* Wi_w    = (const float*)d_in[side * 10 + 4];
    const float* Wi_b    = (const float*)d_in[side * 10 + 5];
    const float* Wh_w    = (const float*)d_in[side * 10 + 6];
    const float* Wh_b    = (const float*)d_in[side * 10 + 7];
    const float* Wo_w    = (const float*)d_in[side * 10 + 8];
    convw<<<(512 * KWI) / 256, 256, 0, stream>>>(wWiB + slot * 512 * KWI, Wi_w, nullptr,
                                                 FATOM, KWI, 512, 0);
    convw<<<(512 * KU) / 256, 256, 0, stream>>>(wWhC + slot * 512 * KU, Wh_w, Wi_w,
                                                526, KU, 512, 2);
    convw<<<(512 * KU) / 256, 256, 0, stream>>>(wWoB + slot * 512 * KU, Wo_w, nullptr,
                                                645, KU, 512, 1);
    bias_comb<<<2, 256, 0, stream>>>(wBC + slot * HD, Wh_b, Wi_b);
    atoms_prep<<<(A_PAD * KWI) / 256, 256, 0, stream>>>(wU + slot * sU, f_atoms);
    bond_gather<<<(A_REAL + 255) / 256, 256, 0, stream>>>(wU + slot * sU, f_bonds, a2b);
  };

  auto mp = [&](int sb, int ns) {
    const int BPS = MT256 * 4;           // 784 blocks per side
    GemmP g;
    // s0 = f_atoms @ Wi^T + bi   (A = wU cols 544.., K=160)
    g = { wU + 544, sU, KU, wWiB, 512ull * KWI, KWI,
          biasWi[sb], biasWi[sb + ns - 1], wS, sX, HD, KWI, BPS };
    gemm_bf16<0, 4><<<ns * BPS, 512, 0, stream>>>(g);
    for (int it = 0; it < 3; ++it) {
      gather6<<<ns * (A_REAL / 4), 256, 0, stream>>>(
          wU, sU, wS, sX, a2aP[sb], a2aP[sb + ns - 1], A_REAL / 4);
      // s = [nei|bond|f_atoms] @ [Wh|0|Wi]^T + (bh+bi)   (x-fold, K=704)
      g = { wU, sU, KU, wWhC, 512ull * KU, KU,
            wBC, wBC + (ns - 1) * HD, wS, sX, HD, KU, BPS };
      gemm_bf16<0, 4><<<ns * BPS, 512, 0, stream>>>(g);
    }
    gather6<<<ns * (A_REAL / 4), 256, 0, stream>>>(
        wU, sU, wS, sX, a2aP[sb], a2aP[sb + ns - 1], A_REAL / 4);
    // h = relu([nei|bond|f_atoms] @ Wo'^T + bo) -> wS (state dead)
    g = { wU, sU, KU, wWoB, 512ull * KU, KU,
          biasWo[sb], biasWo[sb + ns - 1], wS, sX, HD, KU, BPS };
    gemm_bf16<2, 4><<<ns * BPS, 512, 0, stream>>>(g);
    readout<<<ns * NMOL, 256, 0, stream>>>(wS, sX, wEnc, sb, NMOL);
  };

  if (NS == 2) {
    prep(0, 0); prep(1, 1);
    mp(0, 2);
  } else {
    prep(0, 0); mp(0, 1);
    prep(1, 0); mp(1, 1);
  }

  const float* ffn1_w = (const float*)d_in[20];
  const float* ffn1_b = (const float*)d_in[21];
  const float* ffn2_w = (const float*)d_in[22];
  const float* ffn2_b = (const float*)d_in[23];

  convw<<<(NHID * 1024) / 256, 256, 0, stream>>>(wF1B, ffn1_w, nullptr, 1024, 1024, NHID, 0);
  GemmP gf = { wEnc, 0, 1024, wF1B, 0, 1024,
               ffn1_b, ffn1_b, wFF1, 0, NHID, 1024, 16 };
  gemm_bf16<2, 2><<<16, 512, 0, stream>>>(gf);
  ffn2_red<<<NMOL, 256, 0, stream>>>(wFF1, ffn2_w, ffn2_b, (float*)d_out);
}